// Round 8
// baseline (421.298 us; speedup 1.0000x reference)
//
#include <hip/hip_runtime.h>
#include <math.h>

#define T_ 768
#define TD (T_*64)
#define EPSF 1e-8f

typedef __attribute__((ext_vector_type(8))) short short8;
typedef __attribute__((ext_vector_type(4))) float f32x4;

__device__ __forceinline__ float wave_sum64(float v) {
#pragma unroll
  for (int m = 32; m >= 1; m >>= 1) v += __shfl_xor(v, m, 64);
  return v;
}
__device__ __forceinline__ float sigmoidf_(float x) { return 1.0f / (1.0f + expf(-x)); }

__device__ __forceinline__ unsigned short f2bf(float x) {
  unsigned int u = __float_as_uint(x);
  u += 0x7fffu + ((u >> 16) & 1u);        // RNE
  return (unsigned short)(u >> 16);
}

// acos(x), x in [0,1): sqrt(1-x)*poly3, |err|<=6.7e-5 (A-S 4.4.45)
__device__ __forceinline__ float acos_pos(float x) {
  float s = sqrtf(fmaxf(1.0f - x, 0.0f));
  return s * (1.5707288f + x * (-0.2121144f + x * (0.0742610f + x * (-0.0187293f))));
}

// simplex proj + renorm; feature row f=[sqrt(p), sqrt(eps/2)/sqrt(p)] bf16
__device__ __forceinline__ void feat_bf(float v, int row, int lane,
                                        unsigned short* __restrict__ Fb) {
  float sp = fmaxf(v, 0.0f) + log1pf(expf(-fabsf(v)));
  float s = wave_sum64(sp);
  float p1 = fmaxf(sp / (s + EPSF), EPSF);
  float s2 = wave_sum64(p1);
  float p = p1 / (s2 + EPSF);
  Fb[row * 128 + lane] = f2bf(sqrtf(p));
  Fb[row * 128 + 64 + lane] = f2bf(sqrtf(5e-9f / p));
}

// features(bseq) + XT(bseq) + fb_w transpose + pass-0 temps + ticket zeroing.
__global__ void __launch_bounds__(256)
phaseA_kernel(const float* __restrict__ bseq, const float* __restrict__ basin_coords,
              const float* __restrict__ temp_w, const float* __restrict__ temp_b,
              const float* __restrict__ fb_w,
              unsigned short* __restrict__ Fb, unsigned short* __restrict__ XTb,
              float* __restrict__ fbwT, float* __restrict__ temps,
              unsigned* __restrict__ tickets) {
  int b = blockIdx.x, tid = threadIdx.x, w = tid >> 6, l = tid & 63;
  int row = b * 4 + w;
  float v = bseq[row * 64 + l];
  feat_bf(v, row, l, Fb);
  XTb[l * 768 + row] = f2bf(v);
  if (b < 128) {                          // 128*256 = 4*64*128
    int idx = b * 256 + tid;
    int ll = idx >> 13, r = idx & 8191, d = r >> 7, k = r & 127;
    fbwT[ll * 8192 + k * 64 + d] = fb_w[ll * 8192 + d * 128 + k];
  }
  if (b < 2 && tid < 192) tickets[b * 192 + tid] = 0;   // 8 layers x 48 rts
  if (b == 191) {
    float t = basin_coords[l] * temp_w[w * 64 + l];
    t = wave_sum64(t);
    if (l == 0) temps[w] = sigmoidf_(t + temp_b[w]) + 0.5f;
  }
}

// Fused layer: QK Gram (MFMA) -> acos/exp (no-max) -> PV partial (MFMA)
// -> atomic-ticket fan-in: last of 4 chunk-blocks per rt does combine+tail.
// grid 192 = rt(48) x chunk(4), 256 thr.
// mode 0: plain+feat; 1: pool + gate(l0) + feat(gated); 2: gate+feat; 3: final
__global__ void __launch_bounds__(256)
layer_fused(const unsigned short* __restrict__ Fbi,
            const unsigned short* __restrict__ XTi,
            const float* __restrict__ temps, int tidx, int lidx,
            float* __restrict__ pvp_g, float* __restrict__ psum_g,
            unsigned* __restrict__ tickets,
            const float* __restrict__ xin, const float* __restrict__ rs_layers,
            int mode, float* __restrict__ xout,
            unsigned short* __restrict__ Fbo, unsigned short* __restrict__ XTo,
            const float* __restrict__ WT, const float* __restrict__ bb,
            const float* __restrict__ prevX,
            float* __restrict__ gateOut, float* __restrict__ poolPart,
            const float* __restrict__ bseq, const float* __restrict__ res_scale,
            float* __restrict__ outp) {
  __shared__ __align__(16) unsigned short Pl[16][200];   // exp weights bf16
  __shared__ float psumP[4][16];
  __shared__ float xs[16][64], ps[16][64];
  __shared__ unsigned oldt;
  int tid = threadIdx.x, w = tid >> 6, l = tid & 63;
  int lr = l & 15, lk = l >> 4;
  int rt = blockIdx.x >> 2, c = blockIdx.x & 3;
  int i0 = rt * 16;

  // ---- QK: A-frags for row-tile rt ----
  const short8* arow = reinterpret_cast<const short8*>(Fbi + (i0 + lr) * 128);
  short8 afr[4];
#pragma unroll
  for (int ks = 0; ks < 4; ks++) afr[ks] = arow[ks * 4 + lk];
  float inv_t = 1.0f / fmaxf(temps[tidx], 1e-6f);

  float sp[4] = {0.f, 0.f, 0.f, 0.f};
#pragma unroll
  for (int jj = 0; jj < 3; jj++) {
    int jt = w + jj * 4;                  // local j-tile 0..11
    int jg = c * 12 + jt;
    const short8* brow = reinterpret_cast<const short8*>(Fbi + (jg * 16 + lr) * 128);
    // two independent 2-chains
    f32x4 accA = {0.f, 0.f, 0.f, 0.f}, accB = {0.f, 0.f, 0.f, 0.f};
    accA = __builtin_amdgcn_mfma_f32_16x16x32_bf16(afr[0], brow[0 * 4 + lk], accA, 0, 0, 0);
    accB = __builtin_amdgcn_mfma_f32_16x16x32_bf16(afr[2], brow[2 * 4 + lk], accB, 0, 0, 0);
    accA = __builtin_amdgcn_mfma_f32_16x16x32_bf16(afr[1], brow[1 * 4 + lk], accA, 0, 0, 0);
    accB = __builtin_amdgcn_mfma_f32_16x16x32_bf16(afr[3], brow[3 * 4 + lk], accB, 0, 0, 0);
#pragma unroll
    for (int r = 0; r < 4; r++) {
      float inner = fminf(fmaxf(accA[r] + accB[r], 0.0f), 1.0f - 1e-6f);
      float e = expf(-2.0f * acos_pos(inner) * inv_t);   // max logit ~0: no-max safe
      Pl[lk * 4 + r][jt * 16 + lr] = f2bf(e);
      sp[r] += e;
    }
  }
#pragma unroll
  for (int m = 1; m <= 8; m <<= 1)
#pragma unroll
    for (int r = 0; r < 4; r++) sp[r] += __shfl_xor(sp[r], m, 64);
  if (lr == 0)
#pragma unroll
    for (int r = 0; r < 4; r++) psumP[w][lk * 4 + r] = sp[r];
  __syncthreads();

  // ---- PV partial: wave w -> cols w*16..+15, K = chunk's 192 j's ----
  {
    f32x4 pA = {0.f, 0.f, 0.f, 0.f}, pB = {0.f, 0.f, 0.f, 0.f};
    const short8* xtrow =
        reinterpret_cast<const short8*>(XTi + (w * 16 + lr) * 768 + c * 192);
#pragma unroll
    for (int ks = 0; ks < 3; ks++) {
      short8 paA = *reinterpret_cast<const short8*>(&Pl[lr][ks * 32 + lk * 8]);
      short8 paB = *reinterpret_cast<const short8*>(&Pl[lr][(ks + 3) * 32 + lk * 8]);
      pA = __builtin_amdgcn_mfma_f32_16x16x32_bf16(paA, xtrow[ks * 4 + lk], pA, 0, 0, 0);
      pB = __builtin_amdgcn_mfma_f32_16x16x32_bf16(paB, xtrow[(ks + 3) * 4 + lk], pB, 0, 0, 0);
    }
    float* dst = pvp_g + (blockIdx.x << 10);
#pragma unroll
    for (int r = 0; r < 4; r++)
      dst[(lk * 4 + r) * 64 + w * 16 + lr] = pA[r] + pB[r];
  }
  if (tid < 16)
    psum_g[blockIdx.x * 16 + tid] =
        psumP[0][tid] + psumP[1][tid] + psumP[2][tid] + psumP[3][tid];

  // ---- ticket fan-in: last chunk-block of this rt does the combine ----
  __threadfence();                        // release my partial stores
  __syncthreads();
  if (tid == 0) oldt = atomicAdd(&tickets[rt], 1u);
  __syncthreads();
  if (oldt != 3u) return;
  __threadfence();                        // acquire others' partials

  // ---- combine: wave w -> rows w*4..w*4+3 ----
  float rs = rs_layers[lidx];
#pragma unroll
  for (int rr = 0; rr < 4; rr++) {
    int row16 = w * 4 + rr, grow = i0 + row16;
    float pv = 0.f, s = 0.f;
#pragma unroll
    for (int cc = 0; cc < 4; cc++) {
      pv += pvp_g[((rt * 4 + cc) << 10) + row16 * 64 + l];
      s += psum_g[(rt * 4 + cc) * 16 + row16];
    }
    float attn = pv / s;
    float xi = xin[grow * 64 + l];
    float xo = xi + rs * (attn - xi);
    xs[row16][l] = xo;
    if (mode == 1 || mode == 2) ps[row16][l] = prevX[grow * 64 + l];
  }
  __syncthreads();

  if (mode == 3) {
    float sc = 0.01f * res_scale[0];
#pragma unroll
    for (int rr = 0; rr < 4; rr++) {
      int row16 = w * 4 + rr, grow = i0 + row16;
      float xo = xs[row16][l];
      outp[grow * 64 + l] = xo + sc * (xo - bseq[grow * 64 + l]);
    }
    return;
  }
  if (mode == 0) {
#pragma unroll
    for (int rr = 0; rr < 4; rr++) {
      int row16 = w * 4 + rr, grow = i0 + row16;
      float xo = xs[row16][l];
      xout[grow * 64 + l] = xo;
      XTo[l * 768 + grow] = f2bf(xo);
      feat_bf(xo, grow, l, Fbo);
    }
    return;
  }
  // gate modes: a = bb + [x, prev] . W^T (WT k-major)
  float a[4];
#pragma unroll
  for (int rr = 0; rr < 4; rr++) a[rr] = bb[l];
  for (int k = 0; k < 64; k++) {
    float wv = WT[k * 64 + l];
#pragma unroll
    for (int rr = 0; rr < 4; rr++) a[rr] += xs[w * 4 + rr][k] * wv;
  }
  for (int k = 0; k < 64; k++) {
    float wv = WT[(64 + k) * 64 + l];
#pragma unroll
    for (int rr = 0; rr < 4; rr++) a[rr] += ps[w * 4 + rr][k] * wv;
  }
#pragma unroll
  for (int rr = 0; rr < 4; rr++) {
    int row16 = w * 4 + rr, grow = i0 + row16;
    float xo = xs[row16][l];
    float g = sigmoidf_(a[rr]);
    float xn = xo * g + ps[row16][l] * (1.0f - g);
    if (mode == 1) {
      xout[grow * 64 + l] = xo;           // ungated pass0-l3 out (prev for pass1 l3)
      gateOut[grow * 64 + l] = xn;        // pass1 l0 input
    } else {
      xout[grow * 64 + l] = xn;
    }
    XTo[l * 768 + grow] = f2bf(xn);
    feat_bf(xn, grow, l, Fbo);
  }
  if (mode == 1 && w == 0) {
    float s = 0.f;
#pragma unroll
    for (int r2 = 0; r2 < 16; r2++) s += xs[r2][l];
    poolPart[rt * 64 + l] = s;
  }
}

// pool reduce -> MLP -> basin update -> temps[4..7]. 1 block, 256 thr.
__global__ void __launch_bounds__(256)
mlp_kernel(const float* __restrict__ poolPart, const float* __restrict__ basin_coords,
           const float* __restrict__ temp_w, const float* __restrict__ temp_b,
           const float* __restrict__ w1, const float* __restrict__ b1,
           const float* __restrict__ w2, const float* __restrict__ b2,
           const float* __restrict__ uw, const float* __restrict__ ub,
           float* __restrict__ temps) {
  __shared__ float part4[4][64];
  __shared__ float pooled[64], h1s[32], aggs[64], bnew[64];
  int tid = threadIdx.x, w = tid >> 6, l = tid & 63;
  {
    float s = 0.f;
    for (int bb = w * 12; bb < w * 12 + 12; bb++) s += poolPart[bb * 64 + l];
    part4[w][l] = s;
  }
  __syncthreads();
  if (tid < 64)
    pooled[tid] = (part4[0][tid] + part4[1][tid] + part4[2][tid] + part4[3][tid]) *
                  (1.0f / 768.0f);
  __syncthreads();
  if (tid < 32) {
    float h = b1[tid];
    for (int k = 0; k < 64; k++) h += w1[tid * 64 + k] * pooled[k];
    h1s[tid] = tanhf(h);
  }
  __syncthreads();
  if (tid < 64) {
    float h = b2[tid];
    for (int k = 0; k < 32; k++) h += w2[tid * 32 + k] * h1s[k];
    aggs[tid] = tanhf(h);
  }
  __syncthreads();
  if (tid < 64) {
    float g = ub[tid];
    for (int k = 0; k < 64; k++) g += uw[tid * 128 + k] * basin_coords[k];
    for (int k = 0; k < 64; k++) g += uw[tid * 128 + 64 + k] * aggs[k];
    g = sigmoidf_(g);
    bnew[tid] = basin_coords[tid] * (1.0f - g) + aggs[tid] * g;
  }
  __syncthreads();
  {
    float t = bnew[l] * temp_w[w * 64 + l];
    t = wave_sum64(t);
    if (l == 0) temps[4 + w] = sigmoidf_(t + temp_b[w]) + 0.5f;
  }
}

extern "C" void kernel_launch(void* const* d_in, const int* in_sizes, int n_in,
                              void* d_out, int out_size, void* d_ws, size_t ws_size,
                              hipStream_t stream) {
  const float* bseq         = (const float*)d_in[0];
  const float* basin_coords = (const float*)d_in[1];
  const float* temp_w       = (const float*)d_in[2];
  const float* temp_b       = (const float*)d_in[3];
  const float* rs_layers    = (const float*)d_in[4];
  const float* fb_w         = (const float*)d_in[5];
  const float* fb_b         = (const float*)d_in[6];
  const float* comp_w1      = (const float*)d_in[7];
  const float* comp_b1      = (const float*)d_in[8];
  const float* comp_w2      = (const float*)d_in[9];
  const float* comp_b2      = (const float*)d_in[10];
  const float* upd_w        = (const float*)d_in[11];
  const float* upd_b        = (const float*)d_in[12];
  const float* res_scale    = (const float*)d_in[13];
  float* out = (float*)d_out;

  float* ws = (float*)d_ws;
  float* xA       = ws;                    // TD
  float* xB       = xA + TD;               // TD
  float* prevb    = xB + TD;               // 4*TD
  float* fbwT     = prevb + 4 * TD;        // 32768
  float* poolPart = fbwT + 32768;          // 48*64
  float* psum_g   = poolPart + 3072;       // 192*16
  float* pvp_g    = psum_g + 3072;         // 192*1024
  float* temps    = pvp_g + 196608;        // 8 (pad 16)
  unsigned* tickets = (unsigned*)(temps + 16);   // 8*48 = 384
  unsigned short* Fb0 = (unsigned short*)(tickets + 384);
  unsigned short* Fb1 = Fb0 + 98304;
  unsigned short* XT0 = Fb1 + 98304;
  unsigned short* XT1 = XT0 + 49152;

  phaseA_kernel<<<192, 256, 0, stream>>>(bseq, basin_coords, temp_w, temp_b, fb_w,
                                         Fb0, XT0, fbwT, temps, tickets);
  // ---- pass 0 ----
  layer_fused<<<192, 256, 0, stream>>>(Fb0, XT0, temps, 0, 0, pvp_g, psum_g, tickets + 0,
                                       bseq, rs_layers, 0, prevb, Fb1, XT1,
                                       nullptr, nullptr, nullptr, nullptr, nullptr,
                                       nullptr, nullptr, nullptr);
  layer_fused<<<192, 256, 0, stream>>>(Fb1, XT1, temps, 1, 1, pvp_g, psum_g, tickets + 48,
                                       prevb, rs_layers, 0, prevb + TD, Fb0, XT0,
                                       nullptr, nullptr, nullptr, nullptr, nullptr,
                                       nullptr, nullptr, nullptr);
  layer_fused<<<192, 256, 0, stream>>>(Fb0, XT0, temps, 2, 2, pvp_g, psum_g, tickets + 96,
                                       prevb + TD, rs_layers, 0, prevb + 2 * TD, Fb1, XT1,
                                       nullptr, nullptr, nullptr, nullptr, nullptr,
                                       nullptr, nullptr, nullptr);
  // step3: residual -> prevb3; pool; gate(l0) -> xA; feat(gated) -> Fb0/XT0
  layer_fused<<<192, 256, 0, stream>>>(Fb1, XT1, temps, 3, 3, pvp_g, psum_g, tickets + 144,
                                       prevb + 2 * TD, rs_layers, 1, prevb + 3 * TD, Fb0, XT0,
                                       fbwT, fb_b, prevb,
                                       xA, poolPart, nullptr, nullptr, nullptr);
  mlp_kernel<<<1, 256, 0, stream>>>(poolPart, basin_coords, temp_w, temp_b,
                                    comp_w1, comp_b1, comp_w2, comp_b2,
                                    upd_w, upd_b, temps);
  // ---- pass 1 ----
  layer_fused<<<192, 256, 0, stream>>>(Fb0, XT0, temps, 4, 0, pvp_g, psum_g, tickets + 192,
                                       xA, rs_layers, 2, xB, Fb1, XT1,
                                       fbwT + 8192, fb_b + 64, prevb + TD,
                                       nullptr, nullptr, nullptr, nullptr, nullptr);
  layer_fused<<<192, 256, 0, stream>>>(Fb1, XT1, temps, 5, 1, pvp_g, psum_g, tickets + 240,
                                       xB, rs_layers, 2, xA, Fb0, XT0,
                                       fbwT + 16384, fb_b + 128, prevb + 2 * TD,
                                       nullptr, nullptr, nullptr, nullptr, nullptr);
  layer_fused<<<192, 256, 0, stream>>>(Fb0, XT0, temps, 6, 2, pvp_g, psum_g, tickets + 288,
                                       xA, rs_layers, 2, xB, Fb1, XT1,
                                       fbwT + 24576, fb_b + 192, prevb + 3 * TD,
                                       nullptr, nullptr, nullptr, nullptr, nullptr);
  layer_fused<<<192, 256, 0, stream>>>(Fb1, XT1, temps, 7, 3, pvp_g, psum_g, tickets + 336,
                                       xB, rs_layers, 3, nullptr, nullptr, nullptr,
                                       nullptr, nullptr, nullptr, nullptr, nullptr,
                                       bseq, res_scale, out);
}

// Round 9
// 304.651 us; speedup vs baseline: 1.3829x; 1.3829x over previous
//
#include <hip/hip_runtime.h>
#include <math.h>

#define T_ 768
#define TD (T_*64)
#define EPSF 1e-8f

typedef __attribute__((ext_vector_type(8))) short short8;
typedef __attribute__((ext_vector_type(4))) float f32x4;

__device__ __forceinline__ float wave_sum64(float v) {
#pragma unroll
  for (int m = 32; m >= 1; m >>= 1) v += __shfl_xor(v, m, 64);
  return v;
}
__device__ __forceinline__ float sigmoidf_(float x) { return 1.0f / (1.0f + expf(-x)); }

__device__ __forceinline__ unsigned short f2bf(float x) {
  unsigned int u = __float_as_uint(x);
  u += 0x7fffu + ((u >> 16) & 1u);        // RNE
  return (unsigned short)(u >> 16);
}

// acos(x), x in [0,1): sqrt(1-x)*poly3, |err|<=6.7e-5 (A-S 4.4.45)
__device__ __forceinline__ float acos_pos(float x) {
  float s = sqrtf(fmaxf(1.0f - x, 0.0f));
  return s * (1.5707288f + x * (-0.2121144f + x * (0.0742610f + x * (-0.0187293f))));
}

// simplex proj + renorm; feature row f=[sqrt(p), sqrt(eps/2)/sqrt(p)] bf16
__device__ __forceinline__ void feat_bf(float v, int row, int lane,
                                        unsigned short* __restrict__ Fb) {
  float sp = fmaxf(v, 0.0f) + log1pf(expf(-fabsf(v)));
  float s = wave_sum64(sp);
  float p1 = fmaxf(sp / (s + EPSF), EPSF);
  float s2 = wave_sum64(p1);
  float p = p1 / (s2 + EPSF);
  Fb[row * 128 + lane] = f2bf(sqrtf(p));
  Fb[row * 128 + 64 + lane] = f2bf(sqrtf(5e-9f / p));
}

// device-coherent (L2-bypassing) 16B store/load: sc0 sc1 per gfx950 ISA
__device__ __forceinline__ void store_sc1(float* p, f32x4 v) {
  asm volatile("global_store_dwordx4 %0, %1, off sc0 sc1" :: "v"(p), "v"(v) : "memory");
}
__device__ __forceinline__ f32x4 load_sc1(const float* p) {
  f32x4 v;
  asm volatile("global_load_dwordx4 %0, %1, off sc0 sc1" : "=v"(v) : "v"(p) : "memory");
  return v;
}

// features(bseq) + XT(bseq) + fb_w transpose + pass-0 temps + ticket zeroing.
__global__ void __launch_bounds__(256)
phaseA_kernel(const float* __restrict__ bseq, const float* __restrict__ basin_coords,
              const float* __restrict__ temp_w, const float* __restrict__ temp_b,
              const float* __restrict__ fb_w,
              unsigned short* __restrict__ Fb, unsigned short* __restrict__ XTb,
              float* __restrict__ fbwT, float* __restrict__ temps,
              unsigned* __restrict__ tickets) {
  int b = blockIdx.x, tid = threadIdx.x, w = tid >> 6, l = tid & 63;
  int row = b * 4 + w;
  float v = bseq[row * 64 + l];
  feat_bf(v, row, l, Fb);
  XTb[l * 768 + row] = f2bf(v);
  if (b < 128) {                          // 128*256 = 4*64*128
    int idx = b * 256 + tid;
    int ll = idx >> 13, r = idx & 8191, d = r >> 7, k = r & 127;
    fbwT[ll * 8192 + k * 64 + d] = fb_w[ll * 8192 + d * 128 + k];
  }
  if (b < 2 && tid < 192) tickets[b * 192 + tid] = 0;   // 8 layers x 48 rts
  if (b == 191) {
    float t = basin_coords[l] * temp_w[w * 64 + l];
    t = wave_sum64(t);
    if (l == 0) temps[w] = sigmoidf_(t + temp_b[w]) + 0.5f;
  }
}

// Fused layer: QK Gram (MFMA) -> acos/exp (no-max) -> PV partial (MFMA)
// -> sc1 partial store -> ticket; winner combines via sc1 loads + tail.
// grid 192 = rt(48) x chunk(4), 256 thr.
// mode 0: plain+feat; 1: pool + gate(l0) + feat(gated); 2: gate+feat; 3: final
__global__ void __launch_bounds__(256, 3)
layer_fused(const unsigned short* __restrict__ Fbi,
            const unsigned short* __restrict__ XTi,
            const float* __restrict__ temps, int tidx, int lidx,
            float* __restrict__ pvp_g, float* __restrict__ psum_g,
            unsigned* __restrict__ tickets,
            const float* __restrict__ xin, const float* __restrict__ rs_layers,
            int mode, float* __restrict__ xout,
            unsigned short* __restrict__ Fbo, unsigned short* __restrict__ XTo,
            const float* __restrict__ WT, const float* __restrict__ bb,
            const float* __restrict__ prevX,
            float* __restrict__ gateOut, float* __restrict__ poolPart,
            const float* __restrict__ bseq, const float* __restrict__ res_scale,
            float* __restrict__ outp) {
  __shared__ __align__(16) unsigned short Pl[16][200];   // exp weights bf16
  __shared__ float psumP[4][16];
  __shared__ float xs[16][64], ps[16][64];
  __shared__ unsigned oldt;
  int tid = threadIdx.x, w = tid >> 6, l = tid & 63;
  int lr = l & 15, lk = l >> 4;
  int rt = blockIdx.x >> 2, c = blockIdx.x & 3;
  int i0 = rt * 16;

  // ---- QK: A-frags for row-tile rt ----
  const short8* arow = reinterpret_cast<const short8*>(Fbi + (i0 + lr) * 128);
  short8 afr[4];
#pragma unroll
  for (int ks = 0; ks < 4; ks++) afr[ks] = arow[ks * 4 + lk];
  float inv_t = 1.0f / fmaxf(temps[tidx], 1e-6f);

  float sp[4] = {0.f, 0.f, 0.f, 0.f};
#pragma unroll
  for (int jj = 0; jj < 3; jj++) {
    int jt = w + jj * 4;                  // local j-tile 0..11
    int jg = c * 12 + jt;
    const short8* brow = reinterpret_cast<const short8*>(Fbi + (jg * 16 + lr) * 128);
    f32x4 accA = {0.f, 0.f, 0.f, 0.f}, accB = {0.f, 0.f, 0.f, 0.f};
    accA = __builtin_amdgcn_mfma_f32_16x16x32_bf16(afr[0], brow[0 * 4 + lk], accA, 0, 0, 0);
    accB = __builtin_amdgcn_mfma_f32_16x16x32_bf16(afr[2], brow[2 * 4 + lk], accB, 0, 0, 0);
    accA = __builtin_amdgcn_mfma_f32_16x16x32_bf16(afr[1], brow[1 * 4 + lk], accA, 0, 0, 0);
    accB = __builtin_amdgcn_mfma_f32_16x16x32_bf16(afr[3], brow[3 * 4 + lk], accB, 0, 0, 0);
#pragma unroll
    for (int r = 0; r < 4; r++) {
      float inner = fminf(fmaxf(accA[r] + accB[r], 0.0f), 1.0f - 1e-6f);
      float e = expf(-2.0f * acos_pos(inner) * inv_t);   // max logit ~0: no-max safe
      Pl[lk * 4 + r][jt * 16 + lr] = f2bf(e);
      sp[r] += e;
    }
  }
#pragma unroll
  for (int m = 1; m <= 8; m <<= 1)
#pragma unroll
    for (int r = 0; r < 4; r++) sp[r] += __shfl_xor(sp[r], m, 64);
  if (lr == 0)
#pragma unroll
    for (int r = 0; r < 4; r++) psumP[w][lk * 4 + r] = sp[r];
  __syncthreads();

  // ---- PV partial: wave w -> cols w*16..+15, K = chunk's 192 j's ----
  f32x4 pvv;
  {
    f32x4 pA = {0.f, 0.f, 0.f, 0.f}, pB = {0.f, 0.f, 0.f, 0.f};
    const short8* xtrow =
        reinterpret_cast<const short8*>(XTi + (w * 16 + lr) * 768 + c * 192);
#pragma unroll
    for (int ks = 0; ks < 3; ks++) {
      short8 paA = *reinterpret_cast<const short8*>(&Pl[lr][ks * 32 + lk * 8]);
      short8 paB = *reinterpret_cast<const short8*>(&Pl[lr][(ks + 3) * 32 + lk * 8]);
      pA = __builtin_amdgcn_mfma_f32_16x16x32_bf16(paA, xtrow[ks * 4 + lk], pA, 0, 0, 0);
      pB = __builtin_amdgcn_mfma_f32_16x16x32_bf16(paB, xtrow[(ks + 3) * 4 + lk], pB, 0, 0, 0);
    }
#pragma unroll
    for (int r = 0; r < 4; r++) pvv[r] = pA[r] + pB[r];
  }
  // sc1 store: thread t's 4 values (rows lk*4+r, col w*16+lr) at [t*4..t*4+3]
  store_sc1(pvp_g + (blockIdx.x << 10) + tid * 4, pvv);
  if (tid < 16) {
    f32x4 s4;
    s4[0] = psumP[0][tid] + psumP[1][tid] + psumP[2][tid] + psumP[3][tid];
    // scalar sc1 store of the row sum
    asm volatile("global_store_dword %0, %1, off sc0 sc1"
                 :: "v"(psum_g + blockIdx.x * 16 + tid), "v"(s4[0]) : "memory");
  }
  asm volatile("s_waitcnt vmcnt(0)" ::: "memory");   // this wave's sc1 stores at IC
  __syncthreads();                                   // all waves done
  if (tid == 0) oldt = atomicAdd(&tickets[rt], 1u);  // device-scope, no fence
  __syncthreads();
  if (oldt != 3u) return;

  // ---- combine (winner only): read all 4 chunks via sc1 ----
  int tw = (l >> 4) * 64 + w * 16 + (l & 15);        // writer thread for (rows w*4.., col l)
  f32x4 pc0 = load_sc1(pvp_g + ((rt * 4 + 0) << 10) + tw * 4);
  f32x4 pc1 = load_sc1(pvp_g + ((rt * 4 + 1) << 10) + tw * 4);
  f32x4 pc2 = load_sc1(pvp_g + ((rt * 4 + 2) << 10) + tw * 4);
  f32x4 pc3 = load_sc1(pvp_g + ((rt * 4 + 3) << 10) + tw * 4);
  f32x4 sc0v = load_sc1(psum_g + (rt * 4 + 0) * 16 + w * 4);
  f32x4 sc1v = load_sc1(psum_g + (rt * 4 + 1) * 16 + w * 4);
  f32x4 sc2v = load_sc1(psum_g + (rt * 4 + 2) * 16 + w * 4);
  f32x4 sc3v = load_sc1(psum_g + (rt * 4 + 3) * 16 + w * 4);
  asm volatile("s_waitcnt vmcnt(0)" ::: "memory");
  __builtin_amdgcn_sched_barrier(0);

  float rs = rs_layers[lidx];
#pragma unroll
  for (int rr = 0; rr < 4; rr++) {
    int row16 = w * 4 + rr, grow = i0 + row16;
    float pv = ((pc0[rr] + pc1[rr]) + pc2[rr]) + pc3[rr];
    float s = ((sc0v[rr] + sc1v[rr]) + sc2v[rr]) + sc3v[rr];
    float attn = pv / s;
    float xi = xin[grow * 64 + l];
    float xo = xi + rs * (attn - xi);
    xs[row16][l] = xo;
    if (mode == 1 || mode == 2) ps[row16][l] = prevX[grow * 64 + l];
  }
  __syncthreads();

  if (mode == 3) {
    float sc = 0.01f * res_scale[0];
#pragma unroll
    for (int rr = 0; rr < 4; rr++) {
      int row16 = w * 4 + rr, grow = i0 + row16;
      float xo = xs[row16][l];
      outp[grow * 64 + l] = xo + sc * (xo - bseq[grow * 64 + l]);
    }
    return;
  }
  if (mode == 0) {
#pragma unroll
    for (int rr = 0; rr < 4; rr++) {
      int row16 = w * 4 + rr, grow = i0 + row16;
      float xo = xs[row16][l];
      xout[grow * 64 + l] = xo;
      XTo[l * 768 + grow] = f2bf(xo);
      feat_bf(xo, grow, l, Fbo);
    }
    return;
  }
  // gate modes: a = bb + [x, prev] . W^T (WT k-major)
  float a[4];
#pragma unroll
  for (int rr = 0; rr < 4; rr++) a[rr] = bb[l];
  for (int k = 0; k < 64; k++) {
    float wv = WT[k * 64 + l];
#pragma unroll
    for (int rr = 0; rr < 4; rr++) a[rr] += xs[w * 4 + rr][k] * wv;
  }
  for (int k = 0; k < 64; k++) {
    float wv = WT[(64 + k) * 64 + l];
#pragma unroll
    for (int rr = 0; rr < 4; rr++) a[rr] += ps[w * 4 + rr][k] * wv;
  }
#pragma unroll
  for (int rr = 0; rr < 4; rr++) {
    int row16 = w * 4 + rr, grow = i0 + row16;
    float xo = xs[row16][l];
    float g = sigmoidf_(a[rr]);
    float xn = xo * g + ps[row16][l] * (1.0f - g);
    if (mode == 1) {
      xout[grow * 64 + l] = xo;           // ungated pass0-l3 out (prev for pass1 l3)
      gateOut[grow * 64 + l] = xn;        // pass1 l0 input
    } else {
      xout[grow * 64 + l] = xn;
    }
    XTo[l * 768 + grow] = f2bf(xn);
    feat_bf(xn, grow, l, Fbo);
  }
  if (mode == 1 && w == 0) {
    float s = 0.f;
#pragma unroll
    for (int r2 = 0; r2 < 16; r2++) s += xs[r2][l];
    poolPart[rt * 64 + l] = s;
  }
}

// pool reduce -> MLP -> basin update -> temps[4..7]. 1 block, 256 thr.
__global__ void __launch_bounds__(256)
mlp_kernel(const float* __restrict__ poolPart, const float* __restrict__ basin_coords,
           const float* __restrict__ temp_w, const float* __restrict__ temp_b,
           const float* __restrict__ w1, const float* __restrict__ b1,
           const float* __restrict__ w2, const float* __restrict__ b2,
           const float* __restrict__ uw, const float* __restrict__ ub,
           float* __restrict__ temps) {
  __shared__ float part4[4][64];
  __shared__ float pooled[64], h1s[32], aggs[64], bnew[64];
  int tid = threadIdx.x, w = tid >> 6, l = tid & 63;
  {
    float s = 0.f;
    for (int bb = w * 12; bb < w * 12 + 12; bb++) s += poolPart[bb * 64 + l];
    part4[w][l] = s;
  }
  __syncthreads();
  if (tid < 64)
    pooled[tid] = (part4[0][tid] + part4[1][tid] + part4[2][tid] + part4[3][tid]) *
                  (1.0f / 768.0f);
  __syncthreads();
  if (tid < 32) {
    float h = b1[tid];
    for (int k = 0; k < 64; k++) h += w1[tid * 64 + k] * pooled[k];
    h1s[tid] = tanhf(h);
  }
  __syncthreads();
  if (tid < 64) {
    float h = b2[tid];
    for (int k = 0; k < 32; k++) h += w2[tid * 32 + k] * h1s[k];
    aggs[tid] = tanhf(h);
  }
  __syncthreads();
  if (tid < 64) {
    float g = ub[tid];
    for (int k = 0; k < 64; k++) g += uw[tid * 128 + k] * basin_coords[k];
    for (int k = 0; k < 64; k++) g += uw[tid * 128 + 64 + k] * aggs[k];
    g = sigmoidf_(g);
    bnew[tid] = basin_coords[tid] * (1.0f - g) + aggs[tid] * g;
  }
  __syncthreads();
  {
    float t = bnew[l] * temp_w[w * 64 + l];
    t = wave_sum64(t);
    if (l == 0) temps[4 + w] = sigmoidf_(t + temp_b[w]) + 0.5f;
  }
}

extern "C" void kernel_launch(void* const* d_in, const int* in_sizes, int n_in,
                              void* d_out, int out_size, void* d_ws, size_t ws_size,
                              hipStream_t stream) {
  const float* bseq         = (const float*)d_in[0];
  const float* basin_coords = (const float*)d_in[1];
  const float* temp_w       = (const float*)d_in[2];
  const float* temp_b       = (const float*)d_in[3];
  const float* rs_layers    = (const float*)d_in[4];
  const float* fb_w         = (const float*)d_in[5];
  const float* fb_b         = (const float*)d_in[6];
  const float* comp_w1      = (const float*)d_in[7];
  const float* comp_b1      = (const float*)d_in[8];
  const float* comp_w2      = (const float*)d_in[9];
  const float* comp_b2      = (const float*)d_in[10];
  const float* upd_w        = (const float*)d_in[11];
  const float* upd_b        = (const float*)d_in[12];
  const float* res_scale    = (const float*)d_in[13];
  float* out = (float*)d_out;

  float* ws = (float*)d_ws;
  float* xA       = ws;                    // TD
  float* xB       = xA + TD;               // TD
  float* prevb    = xB + TD;               // 4*TD
  float* fbwT     = prevb + 4 * TD;        // 32768
  float* poolPart = fbwT + 32768;          // 48*64
  float* psum_g   = poolPart + 3072;       // 192*16
  float* pvp_g    = psum_g + 3072;         // 192*1024
  float* temps    = pvp_g + 196608;        // 8 (pad 16)
  unsigned* tickets = (unsigned*)(temps + 16);   // 8*48 = 384
  unsigned short* Fb0 = (unsigned short*)(tickets + 384);
  unsigned short* Fb1 = Fb0 + 98304;
  unsigned short* XT0 = Fb1 + 98304;
  unsigned short* XT1 = XT0 + 49152;

  phaseA_kernel<<<192, 256, 0, stream>>>(bseq, basin_coords, temp_w, temp_b, fb_w,
                                         Fb0, XT0, fbwT, temps, tickets);
  // ---- pass 0 ----
  layer_fused<<<192, 256, 0, stream>>>(Fb0, XT0, temps, 0, 0, pvp_g, psum_g, tickets + 0,
                                       bseq, rs_layers, 0, prevb, Fb1, XT1,
                                       nullptr, nullptr, nullptr, nullptr, nullptr,
                                       nullptr, nullptr, nullptr);
  layer_fused<<<192, 256, 0, stream>>>(Fb1, XT1, temps, 1, 1, pvp_g, psum_g, tickets + 48,
                                       prevb, rs_layers, 0, prevb + TD, Fb0, XT0,
                                       nullptr, nullptr, nullptr, nullptr, nullptr,
                                       nullptr, nullptr, nullptr);
  layer_fused<<<192, 256, 0, stream>>>(Fb0, XT0, temps, 2, 2, pvp_g, psum_g, tickets + 96,
                                       prevb + TD, rs_layers, 0, prevb + 2 * TD, Fb1, XT1,
                                       nullptr, nullptr, nullptr, nullptr, nullptr,
                                       nullptr, nullptr, nullptr);
  // step3: residual -> prevb3; pool; gate(l0) -> xA; feat(gated) -> Fb0/XT0
  layer_fused<<<192, 256, 0, stream>>>(Fb1, XT1, temps, 3, 3, pvp_g, psum_g, tickets + 144,
                                       prevb + 2 * TD, rs_layers, 1, prevb + 3 * TD, Fb0, XT0,
                                       fbwT, fb_b, prevb,
                                       xA, poolPart, nullptr, nullptr, nullptr);
  mlp_kernel<<<1, 256, 0, stream>>>(poolPart, basin_coords, temp_w, temp_b,
                                    comp_w1, comp_b1, comp_w2, comp_b2,
                                    upd_w, upd_b, temps);
  // ---- pass 1 ----
  layer_fused<<<192, 256, 0, stream>>>(Fb0, XT0, temps, 4, 0, pvp_g, psum_g, tickets + 192,
                                       xA, rs_layers, 2, xB, Fb1, XT1,
                                       fbwT + 8192, fb_b + 64, prevb + TD,
                                       nullptr, nullptr, nullptr, nullptr, nullptr);
  layer_fused<<<192, 256, 0, stream>>>(Fb1, XT1, temps, 5, 1, pvp_g, psum_g, tickets + 240,
                                       xB, rs_layers, 2, xA, Fb0, XT0,
                                       fbwT + 16384, fb_b + 128, prevb + 2 * TD,
                                       nullptr, nullptr, nullptr, nullptr, nullptr);
  layer_fused<<<192, 256, 0, stream>>>(Fb0, XT0, temps, 6, 2, pvp_g, psum_g, tickets + 288,
                                       xA, rs_layers, 2, xB, Fb1, XT1,
                                       fbwT + 24576, fb_b + 192, prevb + 3 * TD,
                                       nullptr, nullptr, nullptr, nullptr, nullptr);
  layer_fused<<<192, 256, 0, stream>>>(Fb1, XT1, temps, 7, 3, pvp_g, psum_g, tickets + 336,
                                       xB, rs_layers, 3, nullptr, nullptr, nullptr,
                                       nullptr, nullptr, nullptr, nullptr, nullptr,
                                       bseq, res_scale, out);
}

// Round 11
// 195.131 us; speedup vs baseline: 2.1591x; 1.5613x over previous
//
#include <hip/hip_runtime.h>
#include <math.h>

#define T_ 768
#define TD (T_*64)
#define EPSF 1e-8f

typedef __attribute__((ext_vector_type(8))) short short8;
typedef __attribute__((ext_vector_type(4))) float f32x4;

__device__ __forceinline__ float wave_sum64(float v) {
#pragma unroll
  for (int m = 32; m >= 1; m >>= 1) v += __shfl_xor(v, m, 64);
  return v;
}
__device__ __forceinline__ float sigmoidf_(float x) { return 1.0f / (1.0f + expf(-x)); }

__device__ __forceinline__ unsigned short f2bf(float x) {
  unsigned int u = __float_as_uint(x);
  u += 0x7fffu + ((u >> 16) & 1u);        // RNE
  return (unsigned short)(u >> 16);
}

// acos(x), x in [0,1): sqrt(1-x)*poly3, |err|<=6.7e-5 (A-S 4.4.45)
__device__ __forceinline__ float acos_pos(float x) {
  float s = sqrtf(fmaxf(1.0f - x, 0.0f));
  return s * (1.5707288f + x * (-0.2121144f + x * (0.0742610f + x * (-0.0187293f))));
}

// simplex proj + renorm; feature row f=[sqrt(p), sqrt(eps/2)/sqrt(p)] bf16
__device__ __forceinline__ void feat_bf(float v, int row, int lane,
                                        unsigned short* __restrict__ Fb) {
  float sp = fmaxf(v, 0.0f) + log1pf(expf(-fabsf(v)));
  float s = wave_sum64(sp);
  float p1 = fmaxf(sp / (s + EPSF), EPSF);
  float s2 = wave_sum64(p1);
  float p = p1 / (s2 + EPSF);
  Fb[row * 128 + lane] = f2bf(sqrtf(p));
  Fb[row * 128 + 64 + lane] = f2bf(sqrtf(5e-9f / p));
}

// features(bseq) + XT(bseq) + fb_w transpose. grid 192x256.
__global__ void __launch_bounds__(256)
phaseA_kernel(const float* __restrict__ bseq, const float* __restrict__ fb_w,
              unsigned short* __restrict__ Fb, unsigned short* __restrict__ XTb,
              float* __restrict__ fbwT) {
  int b = blockIdx.x, tid = threadIdx.x, w = tid >> 6, l = tid & 63;
  int row = b * 4 + w;
  float v = bseq[row * 64 + l];
  feat_bf(v, row, l, Fb);
  XTb[l * 768 + row] = f2bf(v);
  if (b < 128) {                          // 128*256 = 4*64*128
    int idx = b * 256 + tid;
    int ll = idx >> 13, r = idx & 8191, d = r >> 7, k = r & 127;
    fbwT[ll * 8192 + k * 64 + d] = fb_w[ll * 8192 + d * 128 + k];
  }
}

// One dispatch per layer. 192 blocks x 256 thr; block owns rows 4b..4b+3.
// A-row duplication trick: A tile row lr holds F[i0+(lr&3)] => C reg r = query r.
// mode 0: plain+feat; 1: pool + gate(l0) + feat(gated); 2: gate+feat; 3: final
__global__ void __launch_bounds__(256)
layer_k(const unsigned short* __restrict__ Fbi,
        const unsigned short* __restrict__ XTi,
        int lidx, int mode, int doMlp,
        const float* __restrict__ tbase,     // basin_coords (steps 0-3) / bnew_g (5-7)
        const float* __restrict__ temp_w, const float* __restrict__ temp_b,
        const float* __restrict__ rs_layers,
        const float* __restrict__ xin, float* __restrict__ xout,
        unsigned short* __restrict__ Fbo, unsigned short* __restrict__ XTo,
        const float* __restrict__ WT, const float* __restrict__ bbias,
        const float* __restrict__ prevX,
        float* __restrict__ gateOut, float* __restrict__ poolPart,
        const float* __restrict__ mlp_pool, const float* __restrict__ basin_coords,
        const float* __restrict__ w1, const float* __restrict__ b1,
        const float* __restrict__ w2, const float* __restrict__ b2,
        const float* __restrict__ uw, const float* __restrict__ ub,
        float* __restrict__ bnew_g,
        const float* __restrict__ bseq, const float* __restrict__ res_scale,
        float* __restrict__ outp) {
  __shared__ __align__(16) unsigned short Pl[4][776];   // P numerators bf16
  __shared__ float sums[4][4];                          // [wave][query]
  __shared__ float pvs[4][64];
  __shared__ float xs[4][64], ps[4][64];
  __shared__ float part4[4][64];
  __shared__ float pooled[64], h1s[32], aggs[64], bnewS[64];
  int tid = threadIdx.x, w = tid >> 6, l = tid & 63;
  int lr = l & 15, lk = l >> 4;
  int b = blockIdx.x, i0 = b * 4;

  // ---- temperature (and redundant MLP+basin update on step 4) ----
  float temp;
  if (doMlp) {
    {
      float s = 0.f;
      for (int bb2 = w * 48; bb2 < w * 48 + 48; bb2++) s += mlp_pool[bb2 * 64 + l];
      part4[w][l] = s;
    }
    __syncthreads();
    if (tid < 64)
      pooled[tid] = (part4[0][tid] + part4[1][tid] + part4[2][tid] + part4[3][tid]) *
                    (1.0f / 768.0f);
    __syncthreads();
    if (tid < 32) {
      float h = b1[tid];
      for (int k = 0; k < 64; k++) h += w1[tid * 64 + k] * pooled[k];
      h1s[tid] = tanhf(h);
    }
    __syncthreads();
    if (tid < 64) {
      float h = b2[tid];
      for (int k = 0; k < 32; k++) h += w2[tid * 32 + k] * h1s[k];
      aggs[tid] = tanhf(h);
    }
    __syncthreads();
    if (tid < 64) {
      float g = ub[tid];
      for (int k = 0; k < 64; k++) g += uw[tid * 128 + k] * basin_coords[k];
      for (int k = 0; k < 64; k++) g += uw[tid * 128 + 64 + k] * aggs[k];
      g = sigmoidf_(g);
      bnewS[tid] = basin_coords[tid] * (1.0f - g) + aggs[tid] * g;
    }
    __syncthreads();
    if (b == 0 && tid < 64) bnew_g[tid] = bnewS[tid];   // publish for steps 5-7
    float v = bnewS[l] * temp_w[lidx * 64 + l];
    v = wave_sum64(v);
    temp = sigmoidf_(v + temp_b[lidx]) + 0.5f;
  } else {
    float v = tbase[l] * temp_w[lidx * 64 + l];
    v = wave_sum64(v);
    temp = sigmoidf_(v + temp_b[lidx]) + 0.5f;
  }
  float inv_t = 1.0f / fmaxf(temp, 1e-6f);

  // ---- QK Gram: 4 queries (dup x4 via lr&3), full j; wave w: j-tiles 12w..12w+11 ----
  const short8* arow = reinterpret_cast<const short8*>(Fbi + (i0 + (lr & 3)) * 128);
  short8 afr[4];
#pragma unroll
  for (int ks = 0; ks < 4; ks++) afr[ks] = arow[ks * 4 + lk];

  float sp[4] = {0.f, 0.f, 0.f, 0.f};
#pragma unroll 4
  for (int jj = 0; jj < 12; jj++) {
    int jt = w * 12 + jj;
    const short8* brow = reinterpret_cast<const short8*>(Fbi + (jt * 16 + lr) * 128);
    f32x4 accA = {0.f, 0.f, 0.f, 0.f}, accB = {0.f, 0.f, 0.f, 0.f};
    accA = __builtin_amdgcn_mfma_f32_16x16x32_bf16(afr[0], brow[0 * 4 + lk], accA, 0, 0, 0);
    accB = __builtin_amdgcn_mfma_f32_16x16x32_bf16(afr[2], brow[2 * 4 + lk], accB, 0, 0, 0);
    accA = __builtin_amdgcn_mfma_f32_16x16x32_bf16(afr[1], brow[1 * 4 + lk], accA, 0, 0, 0);
    accB = __builtin_amdgcn_mfma_f32_16x16x32_bf16(afr[3], brow[3 * 4 + lk], accB, 0, 0, 0);
#pragma unroll
    for (int r = 0; r < 4; r++) {
      float inner = fminf(fmaxf(accA[r] + accB[r], 0.0f), 1.0f - 1e-6f);
      float e = expf(-2.0f * acos_pos(inner) * inv_t);   // max logit ~0: no-max safe
      if (lk == 0) Pl[r][jt * 16 + lr] = f2bf(e);
      sp[r] += e;                                        // lk-copies identical
    }
  }
#pragma unroll
  for (int m = 1; m <= 8; m <<= 1)
#pragma unroll
    for (int r = 0; r < 4; r++) sp[r] += __shfl_xor(sp[r], m, 64);
  if (l == 0)
#pragma unroll
    for (int r = 0; r < 4; r++) sums[w][r] = sp[r];
  __syncthreads();

  // ---- PV: wave w -> cols w*16..+15, K=768 in 2 chains of 12 ksteps ----
  {
    f32x4 pA = {0.f, 0.f, 0.f, 0.f}, pB = {0.f, 0.f, 0.f, 0.f};
    const short8* xtrow = reinterpret_cast<const short8*>(XTi + (w * 16 + lr) * 768);
#pragma unroll 4
    for (int ks = 0; ks < 12; ks++) {
      short8 paA = *reinterpret_cast<const short8*>(&Pl[lr & 3][ks * 32 + lk * 8]);
      short8 paB = *reinterpret_cast<const short8*>(&Pl[lr & 3][(ks + 12) * 32 + lk * 8]);
      pA = __builtin_amdgcn_mfma_f32_16x16x32_bf16(paA, xtrow[ks * 4 + lk], pA, 0, 0, 0);
      pB = __builtin_amdgcn_mfma_f32_16x16x32_bf16(paB, xtrow[(ks + 12) * 4 + lk], pB, 0, 0, 0);
    }
    if (lk == 0)
#pragma unroll
      for (int r = 0; r < 4; r++) pvs[r][w * 16 + lr] = pA[r] + pB[r];
  }
  __syncthreads();

  // ---- normalize + residual: wave w -> row w ----
  int row = i0 + w;
  float stot = sums[0][w] + sums[1][w] + sums[2][w] + sums[3][w];
  float attn = pvs[w][l] / stot;
  float xi = xin[row * 64 + l];
  float xo = xi + rs_layers[lidx] * (attn - xi);
  xs[w][l] = xo;
  if (mode == 1 || mode == 2) ps[w][l] = prevX[row * 64 + l];
  __syncthreads();

  // ---- tails ----
  if (mode == 3) {
    outp[row * 64 + l] = xo + 0.01f * res_scale[0] * (xo - bseq[row * 64 + l]);
    return;
  }
  if (mode == 0) {
    xout[row * 64 + l] = xo;
    XTo[l * 768 + row] = f2bf(xo);
    feat_bf(xo, row, l, Fbo);
    return;
  }
  // gate: a = bbias + [x, prev] . W^T   (WT is (128,64) k-major)
  float a = bbias[l];
#pragma unroll 8
  for (int k = 0; k < 64; k++) a += xs[w][k] * WT[k * 64 + l];
#pragma unroll 8
  for (int k = 0; k < 64; k++) a += ps[w][k] * WT[(64 + k) * 64 + l];
  float g = sigmoidf_(a);
  float xn = xo * g + ps[w][l] * (1.0f - g);
  if (mode == 1) {
    xout[row * 64 + l] = xo;              // ungated pass0-l3 out (prev for pass1 l3)
    gateOut[row * 64 + l] = xn;           // pass1 l0 input
  } else {
    xout[row * 64 + l] = xn;
  }
  XTo[l * 768 + row] = f2bf(xn);
  feat_bf(xn, row, l, Fbo);
  if (mode == 1 && w == 0)
    poolPart[b * 64 + l] = xs[0][l] + xs[1][l] + xs[2][l] + xs[3][l];
}

extern "C" void kernel_launch(void* const* d_in, const int* in_sizes, int n_in,
                              void* d_out, int out_size, void* d_ws, size_t ws_size,
                              hipStream_t stream) {
  const float* bseq         = (const float*)d_in[0];
  const float* basin_coords = (const float*)d_in[1];
  const float* temp_w       = (const float*)d_in[2];
  const float* temp_b       = (const float*)d_in[3];
  const float* rs_layers    = (const float*)d_in[4];
  const float* fb_w         = (const float*)d_in[5];
  const float* fb_b         = (const float*)d_in[6];
  const float* comp_w1      = (const float*)d_in[7];
  const float* comp_b1      = (const float*)d_in[8];
  const float* comp_w2      = (const float*)d_in[9];
  const float* comp_b2      = (const float*)d_in[10];
  const float* upd_w        = (const float*)d_in[11];
  const float* upd_b        = (const float*)d_in[12];
  const float* res_scale    = (const float*)d_in[13];
  float* out = (float*)d_out;

  float* ws = (float*)d_ws;
  float* xA       = ws;                    // TD
  float* xB       = xA + TD;               // TD
  float* prevb    = xB + TD;               // 4*TD
  float* fbwT     = prevb + 4 * TD;        // 32768
  float* poolPart = fbwT + 32768;          // 192*64
  float* bnew_g   = poolPart + 12288;      // 64 (pad 80)
  unsigned short* Fb0 = (unsigned short*)(bnew_g + 80);
  unsigned short* Fb1 = Fb0 + 98304;
  unsigned short* XT0 = Fb1 + 98304;
  unsigned short* XT1 = XT0 + 49152;

  phaseA_kernel<<<192, 256, 0, stream>>>(bseq, fb_w, Fb0, XT0, fbwT);

  // ---- pass 0, layer 0 ----
  layer_k<<<192, 256, 0, stream>>>(
      /*Fbi*/ Fb0, /*XTi*/ XT0, /*lidx*/ 0, /*mode*/ 0, /*doMlp*/ 0,
      /*tbase*/ basin_coords, /*temp_w*/ temp_w, /*temp_b*/ temp_b,
      /*rs_layers*/ rs_layers, /*xin*/ bseq, /*xout*/ prevb,
      /*Fbo*/ Fb1, /*XTo*/ XT1,
      /*WT*/ nullptr, /*bbias*/ nullptr, /*prevX*/ nullptr,
      /*gateOut*/ nullptr, /*poolPart*/ nullptr,
      /*mlp_pool*/ nullptr, /*basin_coords*/ nullptr,
      /*w1*/ nullptr, /*b1*/ nullptr, /*w2*/ nullptr, /*b2*/ nullptr,
      /*uw*/ nullptr, /*ub*/ nullptr, /*bnew_g*/ nullptr,
      /*bseq*/ nullptr, /*res_scale*/ nullptr, /*outp*/ nullptr);
  // ---- pass 0, layer 1 ----
  layer_k<<<192, 256, 0, stream>>>(
      /*Fbi*/ Fb1, /*XTi*/ XT1, /*lidx*/ 1, /*mode*/ 0, /*doMlp*/ 0,
      /*tbase*/ basin_coords, /*temp_w*/ temp_w, /*temp_b*/ temp_b,
      /*rs_layers*/ rs_layers, /*xin*/ prevb, /*xout*/ prevb + TD,
      /*Fbo*/ Fb0, /*XTo*/ XT0,
      /*WT*/ nullptr, /*bbias*/ nullptr, /*prevX*/ nullptr,
      /*gateOut*/ nullptr, /*poolPart*/ nullptr,
      /*mlp_pool*/ nullptr, /*basin_coords*/ nullptr,
      /*w1*/ nullptr, /*b1*/ nullptr, /*w2*/ nullptr, /*b2*/ nullptr,
      /*uw*/ nullptr, /*ub*/ nullptr, /*bnew_g*/ nullptr,
      /*bseq*/ nullptr, /*res_scale*/ nullptr, /*outp*/ nullptr);
  // ---- pass 0, layer 2 ----
  layer_k<<<192, 256, 0, stream>>>(
      /*Fbi*/ Fb0, /*XTi*/ XT0, /*lidx*/ 2, /*mode*/ 0, /*doMlp*/ 0,
      /*tbase*/ basin_coords, /*temp_w*/ temp_w, /*temp_b*/ temp_b,
      /*rs_layers*/ rs_layers, /*xin*/ prevb + TD, /*xout*/ prevb + 2 * TD,
      /*Fbo*/ Fb1, /*XTo*/ XT1,
      /*WT*/ nullptr, /*bbias*/ nullptr, /*prevX*/ nullptr,
      /*gateOut*/ nullptr, /*poolPart*/ nullptr,
      /*mlp_pool*/ nullptr, /*basin_coords*/ nullptr,
      /*w1*/ nullptr, /*b1*/ nullptr, /*w2*/ nullptr, /*b2*/ nullptr,
      /*uw*/ nullptr, /*ub*/ nullptr, /*bnew_g*/ nullptr,
      /*bseq*/ nullptr, /*res_scale*/ nullptr, /*outp*/ nullptr);
  // ---- pass 0, layer 3: residual->prevb3; pool; gate(l0)->xA; feat(gated)->Fb0/XT0 ----
  layer_k<<<192, 256, 0, stream>>>(
      /*Fbi*/ Fb1, /*XTi*/ XT1, /*lidx*/ 3, /*mode*/ 1, /*doMlp*/ 0,
      /*tbase*/ basin_coords, /*temp_w*/ temp_w, /*temp_b*/ temp_b,
      /*rs_layers*/ rs_layers, /*xin*/ prevb + 2 * TD, /*xout*/ prevb + 3 * TD,
      /*Fbo*/ Fb0, /*XTo*/ XT0,
      /*WT*/ fbwT, /*bbias*/ fb_b, /*prevX*/ prevb,
      /*gateOut*/ xA, /*poolPart*/ poolPart,
      /*mlp_pool*/ nullptr, /*basin_coords*/ nullptr,
      /*w1*/ nullptr, /*b1*/ nullptr, /*w2*/ nullptr, /*b2*/ nullptr,
      /*uw*/ nullptr, /*ub*/ nullptr, /*bnew_g*/ nullptr,
      /*bseq*/ nullptr, /*res_scale*/ nullptr, /*outp*/ nullptr);
  // ---- pass 1, layer 0 (does MLP/basin update in-prologue) ----
  layer_k<<<192, 256, 0, stream>>>(
      /*Fbi*/ Fb0, /*XTi*/ XT0, /*lidx*/ 0, /*mode*/ 2, /*doMlp*/ 1,
      /*tbase*/ nullptr, /*temp_w*/ temp_w, /*temp_b*/ temp_b,
      /*rs_layers*/ rs_layers, /*xin*/ xA, /*xout*/ xB,
      /*Fbo*/ Fb1, /*XTo*/ XT1,
      /*WT*/ fbwT + 8192, /*bbias*/ fb_b + 64, /*prevX*/ prevb + TD,
      /*gateOut*/ nullptr, /*poolPart*/ nullptr,
      /*mlp_pool*/ poolPart, /*basin_coords*/ basin_coords,
      /*w1*/ comp_w1, /*b1*/ comp_b1, /*w2*/ comp_w2, /*b2*/ comp_b2,
      /*uw*/ upd_w, /*ub*/ upd_b, /*bnew_g*/ bnew_g,
      /*bseq*/ nullptr, /*res_scale*/ nullptr, /*outp*/ nullptr);
  // ---- pass 1, layer 1 ----
  layer_k<<<192, 256, 0, stream>>>(
      /*Fbi*/ Fb1, /*XTi*/ XT1, /*lidx*/ 1, /*mode*/ 2, /*doMlp*/ 0,
      /*tbase*/ bnew_g, /*temp_w*/ temp_w, /*temp_b*/ temp_b,
      /*rs_layers*/ rs_layers, /*xin*/ xB, /*xout*/ xA,
      /*Fbo*/ Fb0, /*XTo*/ XT0,
      /*WT*/ fbwT + 16384, /*bbias*/ fb_b + 128, /*prevX*/ prevb + 2 * TD,
      /*gateOut*/ nullptr, /*poolPart*/ nullptr,
      /*mlp_pool*/ nullptr, /*basin_coords*/ nullptr,
      /*w1*/ nullptr, /*b1*/ nullptr, /*w2*/ nullptr, /*b2*/ nullptr,
      /*uw*/ nullptr, /*ub*/ nullptr, /*bnew_g*/ nullptr,
      /*bseq*/ nullptr, /*res_scale*/ nullptr, /*outp*/ nullptr);
  // ---- pass 1, layer 2 ----
  layer_k<<<192, 256, 0, stream>>>(
      /*Fbi*/ Fb0, /*XTi*/ XT0, /*lidx*/ 2, /*mode*/ 2, /*doMlp*/ 0,
      /*tbase*/ bnew_g, /*temp_w*/ temp_w, /*temp_b*/ temp_b,
      /*rs_layers*/ rs_layers, /*xin*/ xA, /*xout*/ xB,
      /*Fbo*/ Fb1, /*XTo*/ XT1,
      /*WT*/ fbwT + 24576, /*bbias*/ fb_b + 192, /*prevX*/ prevb + 3 * TD,
      /*gateOut*/ nullptr, /*poolPart*/ nullptr,
      /*mlp_pool*/ nullptr, /*basin_coords*/ nullptr,
      /*w1*/ nullptr, /*b1*/ nullptr, /*w2*/ nullptr, /*b2*/ nullptr,
      /*uw*/ nullptr, /*ub*/ nullptr, /*bnew_g*/ nullptr,
      /*bseq*/ nullptr, /*res_scale*/ nullptr, /*outp*/ nullptr);
  // ---- pass 1, layer 3: final output ----
  layer_k<<<192, 256, 0, stream>>>(
      /*Fbi*/ Fb1, /*XTi*/ XT1, /*lidx*/ 3, /*mode*/ 3, /*doMlp*/ 0,
      /*tbase*/ bnew_g, /*temp_w*/ temp_w, /*temp_b*/ temp_b,
      /*rs_layers*/ rs_layers, /*xin*/ xB, /*xout*/ nullptr,
      /*Fbo*/ nullptr, /*XTo*/ nullptr,
      /*WT*/ nullptr, /*bbias*/ nullptr, /*prevX*/ nullptr,
      /*gateOut*/ nullptr, /*poolPart*/ nullptr,
      /*mlp_pool*/ nullptr, /*basin_coords*/ nullptr,
      /*w1*/ nullptr, /*b1*/ nullptr, /*w2*/ nullptr, /*b2*/ nullptr,
      /*uw*/ nullptr, /*ub*/ nullptr, /*bnew_g*/ nullptr,
      /*bseq*/ bseq, /*res_scale*/ res_scale, /*outp*/ out);
}

// Round 12
// 138.170 us; speedup vs baseline: 3.0491x; 1.4123x over previous
//
#include <hip/hip_runtime.h>
#include <math.h>

#define T_ 768
#define TD (T_*64)
#define EPSF 1e-8f

typedef __attribute__((ext_vector_type(8))) short short8;
typedef __attribute__((ext_vector_type(4))) float f32x4;

__device__ __forceinline__ float wave_sum64(float v) {
#pragma unroll
  for (int m = 32; m >= 1; m >>= 1) v += __shfl_xor(v, m, 64);
  return v;
}
__device__ __forceinline__ float sigmoidf_(float x) { return 1.0f / (1.0f + expf(-x)); }

__device__ __forceinline__ unsigned short f2bf(float x) {
  unsigned int u = __float_as_uint(x);
  u += 0x7fffu + ((u >> 16) & 1u);        // RNE
  return (unsigned short)(u >> 16);
}

// acos(x), x in [0,1): sqrt(1-x)*poly3, |err|<=6.7e-5 (A-S 4.4.45)
__device__ __forceinline__ float acos_pos(float x) {
  float s = sqrtf(fmaxf(1.0f - x, 0.0f));
  return s * (1.5707288f + x * (-0.2121144f + x * (0.0742610f + x * (-0.0187293f))));
}

// simplex proj + renorm; feature row f=[sqrt(p), sqrt(eps/2)/sqrt(p)] bf16
__device__ __forceinline__ void feat_bf(float v, int row, int lane,
                                        unsigned short* __restrict__ Fb) {
  float sp = fmaxf(v, 0.0f) + log1pf(expf(-fabsf(v)));
  float s = wave_sum64(sp);
  float p1 = fmaxf(sp / (s + EPSF), EPSF);
  float s2 = wave_sum64(p1);
  float p = p1 / (s2 + EPSF);
  Fb[row * 128 + lane] = f2bf(sqrtf(p));
  Fb[row * 128 + 64 + lane] = f2bf(sqrtf(5e-9f / p));
}

// features(bseq) + XT(bseq) + fb_w transpose. grid 192x256.
__global__ void __launch_bounds__(256)
phaseA_kernel(const float* __restrict__ bseq, const float* __restrict__ fb_w,
              unsigned short* __restrict__ Fb, unsigned short* __restrict__ XTb,
              float* __restrict__ fbwT) {
  int b = blockIdx.x, tid = threadIdx.x, w = tid >> 6, l = tid & 63;
  int row = b * 4 + w;
  float v = bseq[row * 64 + l];
  feat_bf(v, row, l, Fb);
  XTb[l * 768 + row] = f2bf(v);
  if (b < 128) {                          // 128*256 = 4*64*128
    int idx = b * 256 + tid;
    int ll = idx >> 13, r = idx & 8191, d = r >> 7, k = r & 127;
    fbwT[ll * 8192 + k * 64 + d] = fb_w[ll * 8192 + d * 128 + k];
  }
}

// One dispatch per layer. 192 blocks x 512 thr (8 waves, 2 waves/SIMD);
// block owns rows 4b..4b+3. A-row dup: A tile row lr holds F[i0+(lr&3)].
// mode 0: plain+feat; 1: pool + gate(l0) + feat(gated); 2: gate+feat; 3: final
__global__ void __launch_bounds__(512)
layer_k(const unsigned short* __restrict__ Fbi,
        const unsigned short* __restrict__ XTi,
        int lidx, int mode, int doMlp,
        const float* __restrict__ tbase,     // basin_coords (steps 0-3) / bnew_g (5-7)
        const float* __restrict__ temp_w, const float* __restrict__ temp_b,
        const float* __restrict__ rs_layers,
        const float* __restrict__ xin, float* __restrict__ xout,
        unsigned short* __restrict__ Fbo, unsigned short* __restrict__ XTo,
        const float* __restrict__ WT, const float* __restrict__ bbias,
        const float* __restrict__ prevX,
        float* __restrict__ gateOut, float* __restrict__ poolPart,
        const float* __restrict__ mlp_pool, const float* __restrict__ basin_coords,
        const float* __restrict__ w1, const float* __restrict__ b1,
        const float* __restrict__ w2, const float* __restrict__ b2,
        const float* __restrict__ uw, const float* __restrict__ ub,
        float* __restrict__ bnew_g,
        const float* __restrict__ bseq, const float* __restrict__ res_scale,
        float* __restrict__ outp) {
  __shared__ __align__(16) unsigned short Pl[4][776];   // P numerators bf16
  __shared__ float sums8[8][4];                         // [wave][query]
  __shared__ float pvs[2][4][64];                       // [K-half][query][col]
  __shared__ float xs[4][64], ps[4][64];
  __shared__ float part8[8][64];
  __shared__ float pooled[64], h1s[32], aggs[64], bnewS[64];
  int tid = threadIdx.x, w = tid >> 6, l = tid & 63;
  int lr = l & 15, lk = l >> 4;
  int b = blockIdx.x, i0 = b * 4;

  // ---- temperature (and redundant MLP+basin update on step 4) ----
  float temp;
  if (doMlp) {
    {
      float s = 0.f;
      for (int bb2 = w * 24; bb2 < w * 24 + 24; bb2++) s += mlp_pool[bb2 * 64 + l];
      part8[w][l] = s;
    }
    __syncthreads();
    if (tid < 64) {
      float s = 0.f;
#pragma unroll
      for (int q = 0; q < 8; q++) s += part8[q][tid];
      pooled[tid] = s * (1.0f / 768.0f);
    }
    __syncthreads();
    if (tid < 32) {
      float h = b1[tid];
      for (int k = 0; k < 64; k++) h += w1[tid * 64 + k] * pooled[k];
      h1s[tid] = tanhf(h);
    }
    __syncthreads();
    if (tid < 64) {
      float h = b2[tid];
      for (int k = 0; k < 32; k++) h += w2[tid * 32 + k] * h1s[k];
      aggs[tid] = tanhf(h);
    }
    __syncthreads();
    if (tid < 64) {
      float g = ub[tid];
      for (int k = 0; k < 64; k++) g += uw[tid * 128 + k] * basin_coords[k];
      for (int k = 0; k < 64; k++) g += uw[tid * 128 + 64 + k] * aggs[k];
      g = sigmoidf_(g);
      bnewS[tid] = basin_coords[tid] * (1.0f - g) + aggs[tid] * g;
    }
    __syncthreads();
    if (b == 0 && tid < 64) bnew_g[tid] = bnewS[tid];   // publish for steps 5-7
    float v = bnewS[l] * temp_w[lidx * 64 + l];
    v = wave_sum64(v);
    temp = sigmoidf_(v + temp_b[lidx]) + 0.5f;
  } else {
    float v = tbase[l] * temp_w[lidx * 64 + l];
    v = wave_sum64(v);
    temp = sigmoidf_(v + temp_b[lidx]) + 0.5f;
  }
  float inv_t = 1.0f / fmaxf(temp, 1e-6f);

  // ---- QK Gram: 4 queries (dup x4 via lr&3); wave w: j-tiles 6w..6w+5 ----
  const short8* arow = reinterpret_cast<const short8*>(Fbi + (i0 + (lr & 3)) * 128);
  short8 afr[4];
#pragma unroll
  for (int ks = 0; ks < 4; ks++) afr[ks] = arow[ks * 4 + lk];

  float sp[4] = {0.f, 0.f, 0.f, 0.f};
#pragma unroll
  for (int jj = 0; jj < 6; jj++) {
    int jt = w * 6 + jj;
    const short8* brow = reinterpret_cast<const short8*>(Fbi + (jt * 16 + lr) * 128);
    f32x4 accA = {0.f, 0.f, 0.f, 0.f}, accB = {0.f, 0.f, 0.f, 0.f};
    accA = __builtin_amdgcn_mfma_f32_16x16x32_bf16(afr[0], brow[0 * 4 + lk], accA, 0, 0, 0);
    accB = __builtin_amdgcn_mfma_f32_16x16x32_bf16(afr[2], brow[2 * 4 + lk], accB, 0, 0, 0);
    accA = __builtin_amdgcn_mfma_f32_16x16x32_bf16(afr[1], brow[1 * 4 + lk], accA, 0, 0, 0);
    accB = __builtin_amdgcn_mfma_f32_16x16x32_bf16(afr[3], brow[3 * 4 + lk], accB, 0, 0, 0);
#pragma unroll
    for (int r = 0; r < 4; r++) {
      float inner = fminf(fmaxf(accA[r] + accB[r], 0.0f), 1.0f - 1e-6f);
      float e = expf(-2.0f * acos_pos(inner) * inv_t);   // max logit ~0: no-max safe
      if (lk == 0) Pl[r][jt * 16 + lr] = f2bf(e);
      sp[r] += e;                                        // lk-copies identical
    }
  }
#pragma unroll
  for (int m = 1; m <= 8; m <<= 1)
#pragma unroll
    for (int r = 0; r < 4; r++) sp[r] += __shfl_xor(sp[r], m, 64);
  if (l == 0)
#pragma unroll
    for (int r = 0; r < 4; r++) sums8[w][r] = sp[r];
  __syncthreads();

  // ---- PV: wave (cg=w&3, kh=w>>2): cols cg*16..+15, K-half kh (384 j) ----
  {
    int cg = w & 3, kh = w >> 2;
    f32x4 pA = {0.f, 0.f, 0.f, 0.f}, pB = {0.f, 0.f, 0.f, 0.f};
    const short8* xtrow =
        reinterpret_cast<const short8*>(XTi + (cg * 16 + lr) * 768 + kh * 384);
#pragma unroll
    for (int ks = 0; ks < 6; ks++) {
      short8 paA = *reinterpret_cast<const short8*>(&Pl[lr & 3][kh * 384 + ks * 32 + lk * 8]);
      short8 paB = *reinterpret_cast<const short8*>(&Pl[lr & 3][kh * 384 + (ks + 6) * 32 + lk * 8]);
      pA = __builtin_amdgcn_mfma_f32_16x16x32_bf16(paA, xtrow[ks * 4 + lk], pA, 0, 0, 0);
      pB = __builtin_amdgcn_mfma_f32_16x16x32_bf16(paB, xtrow[(ks + 6) * 4 + lk], pB, 0, 0, 0);
    }
    if (lk == 0)
#pragma unroll
      for (int r = 0; r < 4; r++) pvs[kh][r][cg * 16 + lr] = pA[r] + pB[r];
  }
  __syncthreads();

  // ---- normalize + residual: waves w and w+4 both handle row rw=w&3 ----
  int rw = w & 3;
  int row = i0 + rw;
  float stot = ((sums8[0][rw] + sums8[1][rw]) + (sums8[2][rw] + sums8[3][rw])) +
               ((sums8[4][rw] + sums8[5][rw]) + (sums8[6][rw] + sums8[7][rw]));
  float attn = (pvs[0][rw][l] + pvs[1][rw][l]) / stot;
  float xi = xin[row * 64 + l];
  float xo = xi + rs_layers[lidx] * (attn - xi);
  xs[rw][l] = xo;                          // duplicate identical write (w, w+4): benign
  if (mode == 1 || mode == 2) ps[rw][l] = prevX[row * 64 + l];
  __syncthreads();

  // ---- tails (waves 4-7 mirror waves 0-3; all writes idempotent) ----
  if (mode == 3) {
    outp[row * 64 + l] = xo + 0.01f * res_scale[0] * (xo - bseq[row * 64 + l]);
    return;
  }
  if (mode == 0) {
    xout[row * 64 + l] = xo;
    XTo[l * 768 + row] = f2bf(xo);
    feat_bf(xo, row, l, Fbo);
    return;
  }
  // gate: a = bbias + [x, prev] . W^T   (WT is (128,64) k-major)
  float a = bbias[l];
#pragma unroll 8
  for (int k = 0; k < 64; k++) a += xs[rw][k] * WT[k * 64 + l];
#pragma unroll 8
  for (int k = 0; k < 64; k++) a += ps[rw][k] * WT[(64 + k) * 64 + l];
  float g = sigmoidf_(a);
  float xn = xo * g + ps[rw][l] * (1.0f - g);
  if (mode == 1) {
    xout[row * 64 + l] = xo;              // ungated pass0-l3 out (prev for pass1 l3)
    gateOut[row * 64 + l] = xn;           // pass1 l0 input
  } else {
    xout[row * 64 + l] = xn;
  }
  XTo[l * 768 + row] = f2bf(xn);
  feat_bf(xn, row, l, Fbo);
  if (mode == 1 && w == 0)
    poolPart[b * 64 + l] = xs[0][l] + xs[1][l] + xs[2][l] + xs[3][l];
}

extern "C" void kernel_launch(void* const* d_in, const int* in_sizes, int n_in,
                              void* d_out, int out_size, void* d_ws, size_t ws_size,
                              hipStream_t stream) {
  const float* bseq         = (const float*)d_in[0];
  const float* basin_coords = (const float*)d_in[1];
  const float* temp_w       = (const float*)d_in[2];
  const float* temp_b       = (const float*)d_in[3];
  const float* rs_layers    = (const float*)d_in[4];
  const float* fb_w         = (const float*)d_in[5];
  const float* fb_b         = (const float*)d_in[6];
  const float* comp_w1      = (const float*)d_in[7];
  const float* comp_b1      = (const float*)d_in[8];
  const float* comp_w2      = (const float*)d_in[9];
  const float* comp_b2      = (const float*)d_in[10];
  const float* upd_w        = (const float*)d_in[11];
  const float* upd_b        = (const float*)d_in[12];
  const float* res_scale    = (const float*)d_in[13];
  float* out = (float*)d_out;

  float* ws = (float*)d_ws;
  float* xA       = ws;                    // TD
  float* xB       = xA + TD;               // TD
  float* prevb    = xB + TD;               // 4*TD
  float* fbwT     = prevb + 4 * TD;        // 32768
  float* poolPart = fbwT + 32768;          // 192*64
  float* bnew_g   = poolPart + 12288;      // 64 (pad 80)
  unsigned short* Fb0 = (unsigned short*)(bnew_g + 80);
  unsigned short* Fb1 = Fb0 + 98304;
  unsigned short* XT0 = Fb1 + 98304;
  unsigned short* XT1 = XT0 + 49152;

  phaseA_kernel<<<192, 256, 0, stream>>>(bseq, fb_w, Fb0, XT0, fbwT);

  // ---- pass 0, layer 0 ----
  layer_k<<<192, 512, 0, stream>>>(
      /*Fbi*/ Fb0, /*XTi*/ XT0, /*lidx*/ 0, /*mode*/ 0, /*doMlp*/ 0,
      /*tbase*/ basin_coords, /*temp_w*/ temp_w, /*temp_b*/ temp_b,
      /*rs_layers*/ rs_layers, /*xin*/ bseq, /*xout*/ prevb,
      /*Fbo*/ Fb1, /*XTo*/ XT1,
      /*WT*/ nullptr, /*bbias*/ nullptr, /*prevX*/ nullptr,
      /*gateOut*/ nullptr, /*poolPart*/ nullptr,
      /*mlp_pool*/ nullptr, /*basin_coords*/ nullptr,
      /*w1*/ nullptr, /*b1*/ nullptr, /*w2*/ nullptr, /*b2*/ nullptr,
      /*uw*/ nullptr, /*ub*/ nullptr, /*bnew_g*/ nullptr,
      /*bseq*/ nullptr, /*res_scale*/ nullptr, /*outp*/ nullptr);
  // ---- pass 0, layer 1 ----
  layer_k<<<192, 512, 0, stream>>>(
      /*Fbi*/ Fb1, /*XTi*/ XT1, /*lidx*/ 1, /*mode*/ 0, /*doMlp*/ 0,
      /*tbase*/ basin_coords, /*temp_w*/ temp_w, /*temp_b*/ temp_b,
      /*rs_layers*/ rs_layers, /*xin*/ prevb, /*xout*/ prevb + TD,
      /*Fbo*/ Fb0, /*XTo*/ XT0,
      /*WT*/ nullptr, /*bbias*/ nullptr, /*prevX*/ nullptr,
      /*gateOut*/ nullptr, /*poolPart*/ nullptr,
      /*mlp_pool*/ nullptr, /*basin_coords*/ nullptr,
      /*w1*/ nullptr, /*b1*/ nullptr, /*w2*/ nullptr, /*b2*/ nullptr,
      /*uw*/ nullptr, /*ub*/ nullptr, /*bnew_g*/ nullptr,
      /*bseq*/ nullptr, /*res_scale*/ nullptr, /*outp*/ nullptr);
  // ---- pass 0, layer 2 ----
  layer_k<<<192, 512, 0, stream>>>(
      /*Fbi*/ Fb0, /*XTi*/ XT0, /*lidx*/ 2, /*mode*/ 0, /*doMlp*/ 0,
      /*tbase*/ basin_coords, /*temp_w*/ temp_w, /*temp_b*/ temp_b,
      /*rs_layers*/ rs_layers, /*xin*/ prevb + TD, /*xout*/ prevb + 2 * TD,
      /*Fbo*/ Fb1, /*XTo*/ XT1,
      /*WT*/ nullptr, /*bbias*/ nullptr, /*prevX*/ nullptr,
      /*gateOut*/ nullptr, /*poolPart*/ nullptr,
      /*mlp_pool*/ nullptr, /*basin_coords*/ nullptr,
      /*w1*/ nullptr, /*b1*/ nullptr, /*w2*/ nullptr, /*b2*/ nullptr,
      /*uw*/ nullptr, /*ub*/ nullptr, /*bnew_g*/ nullptr,
      /*bseq*/ nullptr, /*res_scale*/ nullptr, /*outp*/ nullptr);
  // ---- pass 0, layer 3: residual->prevb3; pool; gate(l0)->xA; feat(gated)->Fb0/XT0 ----
  layer_k<<<192, 512, 0, stream>>>(
      /*Fbi*/ Fb1, /*XTi*/ XT1, /*lidx*/ 3, /*mode*/ 1, /*doMlp*/ 0,
      /*tbase*/ basin_coords, /*temp_w*/ temp_w, /*temp_b*/ temp_b,
      /*rs_layers*/ rs_layers, /*xin*/ prevb + 2 * TD, /*xout*/ prevb + 3 * TD,
      /*Fbo*/ Fb0, /*XTo*/ XT0,
      /*WT*/ fbwT, /*bbias*/ fb_b, /*prevX*/ prevb,
      /*gateOut*/ xA, /*poolPart*/ poolPart,
      /*mlp_pool*/ nullptr, /*basin_coords*/ nullptr,
      /*w1*/ nullptr, /*b1*/ nullptr, /*w2*/ nullptr, /*b2*/ nullptr,
      /*uw*/ nullptr, /*ub*/ nullptr, /*bnew_g*/ nullptr,
      /*bseq*/ nullptr, /*res_scale*/ nullptr, /*outp*/ nullptr);
  // ---- pass 1, layer 0 (does MLP/basin update in-prologue) ----
  layer_k<<<192, 512, 0, stream>>>(
      /*Fbi*/ Fb0, /*XTi*/ XT0, /*lidx*/ 0, /*mode*/ 2, /*doMlp*/ 1,
      /*tbase*/ nullptr, /*temp_w*/ temp_w, /*temp_b*/ temp_b,
      /*rs_layers*/ rs_layers, /*xin*/ xA, /*xout*/ xB,
      /*Fbo*/ Fb1, /*XTo*/ XT1,
      /*WT*/ fbwT + 8192, /*bbias*/ fb_b + 64, /*prevX*/ prevb + TD,
      /*gateOut*/ nullptr, /*poolPart*/ nullptr,
      /*mlp_pool*/ poolPart, /*basin_coords*/ basin_coords,
      /*w1*/ comp_w1, /*b1*/ comp_b1, /*w2*/ comp_w2, /*b2*/ comp_b2,
      /*uw*/ upd_w, /*ub*/ upd_b, /*bnew_g*/ bnew_g,
      /*bseq*/ nullptr, /*res_scale*/ nullptr, /*outp*/ nullptr);
  // ---- pass 1, layer 1 ----
  layer_k<<<192, 512, 0, stream>>>(
      /*Fbi*/ Fb1, /*XTi*/ XT1, /*lidx*/ 1, /*mode*/ 2, /*doMlp*/ 0,
      /*tbase*/ bnew_g, /*temp_w*/ temp_w, /*temp_b*/ temp_b,
      /*rs_layers*/ rs_layers, /*xin*/ xB, /*xout*/ xA,
      /*Fbo*/ Fb0, /*XTo*/ XT0,
      /*WT*/ fbwT + 16384, /*bbias*/ fb_b + 128, /*prevX*/ prevb + 2 * TD,
      /*gateOut*/ nullptr, /*poolPart*/ nullptr,
      /*mlp_pool*/ nullptr, /*basin_coords*/ nullptr,
      /*w1*/ nullptr, /*b1*/ nullptr, /*w2*/ nullptr, /*b2*/ nullptr,
      /*uw*/ nullptr, /*ub*/ nullptr, /*bnew_g*/ nullptr,
      /*bseq*/ nullptr, /*res_scale*/ nullptr, /*outp*/ nullptr);
  // ---- pass 1, layer 2 ----
  layer_k<<<192, 512, 0, stream>>>(
      /*Fbi*/ Fb0, /*XTi*/ XT0, /*lidx*/ 2, /*mode*/ 2, /*doMlp*/ 0,
      /*tbase*/ bnew_g, /*temp_w*/ temp_w, /*temp_b*/ temp_b,
      /*rs_layers*/ rs_layers, /*xin*/ xA, /*xout*/ xB,
      /*Fbo*/ Fb1, /*XTo*/ XT1,
      /*WT*/ fbwT + 24576, /*bbias*/ fb_b + 192, /*prevX*/ prevb + 3 * TD,
      /*gateOut*/ nullptr, /*poolPart*/ nullptr,
      /*mlp_pool*/ nullptr, /*basin_coords*/ nullptr,
      /*w1*/ nullptr, /*b1*/ nullptr, /*w2*/ nullptr, /*b2*/ nullptr,
      /*uw*/ nullptr, /*ub*/ nullptr, /*bnew_g*/ nullptr,
      /*bseq*/ nullptr, /*res_scale*/ nullptr, /*outp*/ nullptr);
  // ---- pass 1, layer 3: final output ----
  layer_k<<<192, 512, 0, stream>>>(
      /*Fbi*/ Fb1, /*XTi*/ XT1, /*lidx*/ 3, /*mode*/ 3, /*doMlp*/ 0,
      /*tbase*/ bnew_g, /*temp_w*/ temp_w, /*temp_b*/ temp_b,
      /*rs_layers*/ rs_layers, /*xin*/ xB, /*xout*/ nullptr,
      /*Fbo*/ nullptr, /*XTo*/ nullptr,
      /*WT*/ nullptr, /*bbias*/ nullptr, /*prevX*/ nullptr,
      /*gateOut*/ nullptr, /*poolPart*/ nullptr,
      /*mlp_pool*/ nullptr, /*basin_coords*/ nullptr,
      /*w1*/ nullptr, /*b1*/ nullptr, /*w2*/ nullptr, /*b2*/ nullptr,
      /*uw*/ nullptr, /*ub*/ nullptr, /*bnew_g*/ nullptr,
      /*bseq*/ bseq, /*res_scale*/ res_scale, /*outp*/ out);
}

// Round 13
// 127.604 us; speedup vs baseline: 3.3016x; 1.0828x over previous
//
#include <hip/hip_runtime.h>
#include <math.h>

#define T_ 768
#define TD (T_*64)
#define EPSF 1e-8f

typedef __attribute__((ext_vector_type(8))) short short8;
typedef __attribute__((ext_vector_type(4))) float f32x4;

__device__ __forceinline__ float wave_sum64(float v) {
#pragma unroll
  for (int m = 32; m >= 1; m >>= 1) v += __shfl_xor(v, m, 64);
  return v;
}
__device__ __forceinline__ float sigmoidf_(float x) { return 1.0f / (1.0f + expf(-x)); }

__device__ __forceinline__ unsigned short f2bf(float x) {
  unsigned int u = __float_as_uint(x);
  u += 0x7fffu + ((u >> 16) & 1u);        // RNE
  return (unsigned short)(u >> 16);
}

// acos(x), x in [0,1): sqrt(1-x)*poly3, |err|<=6.7e-5 (A-S 4.4.45)
__device__ __forceinline__ float acos_pos(float x) {
  float s = sqrtf(fmaxf(1.0f - x, 0.0f));
  return s * (1.5707288f + x * (-0.2121144f + x * (0.0742610f + x * (-0.0187293f))));
}

// simplex proj + renorm; feature row f = sqrt(p) (64 bf16). eps-term dropped:
// contributes ~2e-5 to inner, far below bf16 noise already present.
__device__ __forceinline__ void feat_bf(float v, int row, int lane,
                                        unsigned short* __restrict__ Fb) {
  float sp = fmaxf(v, 0.0f) + log1pf(expf(-fabsf(v)));
  float s = wave_sum64(sp);
  float p1 = fmaxf(sp / (s + EPSF), EPSF);
  float s2 = wave_sum64(p1);
  float p = p1 / (s2 + EPSF);
  Fb[row * 64 + lane] = f2bf(sqrtf(p));
}

// features(bseq) + XT(bseq) + fb_w transpose. grid 192x256.
__global__ void __launch_bounds__(256)
phaseA_kernel(const float* __restrict__ bseq, const float* __restrict__ fb_w,
              unsigned short* __restrict__ Fb, unsigned short* __restrict__ XTb,
              float* __restrict__ fbwT) {
  int b = blockIdx.x, tid = threadIdx.x, w = tid >> 6, l = tid & 63;
  int row = b * 4 + w;
  float v = bseq[row * 64 + l];
  feat_bf(v, row, l, Fb);
  XTb[l * 768 + row] = f2bf(v);
  if (b < 128) {                          // 128*256 = 4*64*128
    int idx = b * 256 + tid;
    int ll = idx >> 13, r = idx & 8191, d = r >> 7, k = r & 127;
    fbwT[ll * 8192 + k * 64 + d] = fb_w[ll * 8192 + d * 128 + k];
  }
}

// One dispatch per layer. 192 blocks x 1024 thr (16 waves, 4 waves/SIMD);
// block owns rows 4b..4b+3. A-row dup: A tile row lr holds F[i0+(lr&3)].
// mode 0: plain+feat; 1: pool + gate(l0) + feat(gated); 2: gate+feat; 3: final
__global__ void __launch_bounds__(1024)
layer_k(const unsigned short* __restrict__ Fbi,
        const unsigned short* __restrict__ XTi,
        int lidx, int mode, int doMlp,
        const float* __restrict__ tbase,     // basin_coords (steps 0-3) / bnew_g (5-7)
        const float* __restrict__ temp_w, const float* __restrict__ temp_b,
        const float* __restrict__ rs_layers,
        const float* __restrict__ xin, float* __restrict__ xout,
        unsigned short* __restrict__ Fbo, unsigned short* __restrict__ XTo,
        const float* __restrict__ WT, const float* __restrict__ bbias,
        const float* __restrict__ prevX,
        float* __restrict__ gateOut, float* __restrict__ poolPart,
        const float* __restrict__ mlp_pool, const float* __restrict__ basin_coords,
        const float* __restrict__ w1, const float* __restrict__ b1,
        const float* __restrict__ w2, const float* __restrict__ b2,
        const float* __restrict__ uw, const float* __restrict__ ub,
        float* __restrict__ bnew_g,
        const float* __restrict__ bseq, const float* __restrict__ res_scale,
        float* __restrict__ outp) {
  __shared__ __align__(16) unsigned short Pl[4][776];   // P numerators bf16
  __shared__ float sums16[16][4];                       // [wave][query]
  __shared__ float pvs[4][4][64];                       // [K-quarter][query][col]
  __shared__ float xs[4][64], ps[4][64];
  __shared__ float part16[16][64];
  __shared__ float pooled[64], h1s[32], aggs[64], bnewS[64];
  int tid = threadIdx.x, w = tid >> 6, l = tid & 63;
  int lr = l & 15, lk = l >> 4;
  int b = blockIdx.x, i0 = b * 4;

  // ---- temperature (and redundant MLP+basin update on step 4) ----
  float temp;
  if (doMlp) {
    {
      float s = 0.f;
      for (int bb2 = w * 12; bb2 < w * 12 + 12; bb2++) s += mlp_pool[bb2 * 64 + l];
      part16[w][l] = s;
    }
    __syncthreads();
    if (tid < 64) {
      float s = 0.f;
#pragma unroll
      for (int q = 0; q < 16; q++) s += part16[q][tid];
      pooled[tid] = s * (1.0f / 768.0f);
    }
    __syncthreads();
    if (tid < 32) {
      float h = b1[tid];
      for (int k = 0; k < 64; k++) h += w1[tid * 64 + k] * pooled[k];
      h1s[tid] = tanhf(h);
    }
    __syncthreads();
    if (tid < 64) {
      float h = b2[tid];
      for (int k = 0; k < 32; k++) h += w2[tid * 32 + k] * h1s[k];
      aggs[tid] = tanhf(h);
    }
    __syncthreads();
    if (tid < 64) {
      float g = ub[tid];
      for (int k = 0; k < 64; k++) g += uw[tid * 128 + k] * basin_coords[k];
      for (int k = 0; k < 64; k++) g += uw[tid * 128 + 64 + k] * aggs[k];
      g = sigmoidf_(g);
      bnewS[tid] = basin_coords[tid] * (1.0f - g) + aggs[tid] * g;
    }
    __syncthreads();
    if (b == 0 && tid < 64) bnew_g[tid] = bnewS[tid];   // publish for steps 5-7
    float v = bnewS[l] * temp_w[lidx * 64 + l];
    v = wave_sum64(v);
    temp = sigmoidf_(v + temp_b[lidx]) + 0.5f;
  } else {
    float v = tbase[l] * temp_w[lidx * 64 + l];
    v = wave_sum64(v);
    temp = sigmoidf_(v + temp_b[lidx]) + 0.5f;
  }
  float inv_t = 1.0f / fmaxf(temp, 1e-6f);

  // ---- QK Gram (K=64): 4 queries (dup x4 via lr&3); wave w: j-tiles 3w..3w+2 ----
  const short8* arow = reinterpret_cast<const short8*>(Fbi + (i0 + (lr & 3)) * 64);
  short8 afr0 = arow[lk], afr1 = arow[4 + lk];

  float sp[4] = {0.f, 0.f, 0.f, 0.f};
#pragma unroll
  for (int jj = 0; jj < 3; jj++) {
    int jt = w * 3 + jj;
    const short8* brow = reinterpret_cast<const short8*>(Fbi + (jt * 16 + lr) * 64);
    f32x4 acc = {0.f, 0.f, 0.f, 0.f};
    acc = __builtin_amdgcn_mfma_f32_16x16x32_bf16(afr0, brow[lk], acc, 0, 0, 0);
    acc = __builtin_amdgcn_mfma_f32_16x16x32_bf16(afr1, brow[4 + lk], acc, 0, 0, 0);
#pragma unroll
    for (int r = 0; r < 4; r++) {
      float inner = fminf(fmaxf(acc[r], 0.0f), 1.0f - 1e-6f);
      float e = expf(-2.0f * acos_pos(inner) * inv_t);   // max logit ~0: no-max safe
      if (lk == 0) Pl[r][jt * 16 + lr] = f2bf(e);
      sp[r] += e;                                        // lk-copies identical
    }
  }
#pragma unroll
  for (int m = 1; m <= 8; m <<= 1)
#pragma unroll
    for (int r = 0; r < 4; r++) sp[r] += __shfl_xor(sp[r], m, 64);
  if (l == 0)
#pragma unroll
    for (int r = 0; r < 4; r++) sums16[w][r] = sp[r];
  __syncthreads();

  // ---- PV: wave (cg=w&3, kq=w>>2): cols cg*16..+15, K-quarter kq (192 j) ----
  {
    int cg = w & 3, kq = w >> 2;
    f32x4 pA = {0.f, 0.f, 0.f, 0.f}, pB = {0.f, 0.f, 0.f, 0.f};
    const short8* xtrow =
        reinterpret_cast<const short8*>(XTi + (cg * 16 + lr) * 768 + kq * 192);
#pragma unroll
    for (int ks = 0; ks < 3; ks++) {
      short8 paA = *reinterpret_cast<const short8*>(&Pl[lr & 3][kq * 192 + ks * 32 + lk * 8]);
      short8 paB = *reinterpret_cast<const short8*>(&Pl[lr & 3][kq * 192 + (ks + 3) * 32 + lk * 8]);
      pA = __builtin_amdgcn_mfma_f32_16x16x32_bf16(paA, xtrow[ks * 4 + lk], pA, 0, 0, 0);
      pB = __builtin_amdgcn_mfma_f32_16x16x32_bf16(paB, xtrow[(ks + 3) * 4 + lk], pB, 0, 0, 0);
    }
    if (lk == 0)
#pragma unroll
      for (int r = 0; r < 4; r++) pvs[kq][r][cg * 16 + lr] = pA[r] + pB[r];
  }
  __syncthreads();

  // ---- normalize + residual: wave-groups all handle row rw=w&3 (idempotent) ----
  int rw = w & 3;
  int row = i0 + rw;
  float stot = 0.f;
#pragma unroll
  for (int q = 0; q < 16; q++) stot += sums16[q][rw];
  float attn = ((pvs[0][rw][l] + pvs[1][rw][l]) + (pvs[2][rw][l] + pvs[3][rw][l])) / stot;
  float xi = xin[row * 64 + l];
  float xo = xi + rs_layers[lidx] * (attn - xi);
  xs[rw][l] = xo;                          // duplicate identical writes: benign
  if (mode == 1 || mode == 2) ps[rw][l] = prevX[row * 64 + l];
  __syncthreads();

  // ---- tails (wave-groups mirror; all writes idempotent) ----
  if (mode == 3) {
    outp[row * 64 + l] = xo + 0.01f * res_scale[0] * (xo - bseq[row * 64 + l]);
    return;
  }
  if (mode == 0) {
    xout[row * 64 + l] = xo;
    XTo[l * 768 + row] = f2bf(xo);
    feat_bf(xo, row, l, Fbo);
    return;
  }
  // gate: a = bbias + [x, prev] . W^T   (WT is (128,64) k-major)
  float a = bbias[l];
#pragma unroll 8
  for (int k = 0; k < 64; k++) a += xs[rw][k] * WT[k * 64 + l];
#pragma unroll 8
  for (int k = 0; k < 64; k++) a += ps[rw][k] * WT[(64 + k) * 64 + l];
  float g = sigmoidf_(a);
  float xn = xo * g + ps[rw][l] * (1.0f - g);
  if (mode == 1) {
    xout[row * 64 + l] = xo;              // ungated pass0-l3 out (prev for pass1 l3)
    gateOut[row * 64 + l] = xn;           // pass1 l0 input
  } else {
    xout[row * 64 + l] = xn;
  }
  XTo[l * 768 + row] = f2bf(xn);
  feat_bf(xn, row, l, Fbo);
  if (mode == 1 && w == 0)
    poolPart[b * 64 + l] = xs[0][l] + xs[1][l] + xs[2][l] + xs[3][l];
}

extern "C" void kernel_launch(void* const* d_in, const int* in_sizes, int n_in,
                              void* d_out, int out_size, void* d_ws, size_t ws_size,
                              hipStream_t stream) {
  const float* bseq         = (const float*)d_in[0];
  const float* basin_coords = (const float*)d_in[1];
  const float* temp_w       = (const float*)d_in[2];
  const float* temp_b       = (const float*)d_in[3];
  const float* rs_layers    = (const float*)d_in[4];
  const float* fb_w         = (const float*)d_in[5];
  const float* fb_b         = (const float*)d_in[6];
  const float* comp_w1      = (const float*)d_in[7];
  const float* comp_b1      = (const float*)d_in[8];
  const float* comp_w2      = (const float*)d_in[9];
  const float* comp_b2      = (const float*)d_in[10];
  const float* upd_w        = (const float*)d_in[11];
  const float* upd_b        = (const float*)d_in[12];
  const float* res_scale    = (const float*)d_in[13];
  float* out = (float*)d_out;

  float* ws = (float*)d_ws;
  float* xA       = ws;                    // TD
  float* xB       = xA + TD;               // TD
  float* prevb    = xB + TD;               // 4*TD
  float* fbwT     = prevb + 4 * TD;        // 32768
  float* poolPart = fbwT + 32768;          // 192*64
  float* bnew_g   = poolPart + 12288;      // 64 (pad 80)
  unsigned short* Fb0 = (unsigned short*)(bnew_g + 80);  // 768*64 bf16
  unsigned short* Fb1 = Fb0 + 49152;
  unsigned short* XT0 = Fb1 + 49152;       // 64*768 bf16
  unsigned short* XT1 = XT0 + 49152;

  phaseA_kernel<<<192, 256, 0, stream>>>(bseq, fb_w, Fb0, XT0, fbwT);

  // ---- pass 0, layer 0 ----
  layer_k<<<192, 1024, 0, stream>>>(
      /*Fbi*/ Fb0, /*XTi*/ XT0, /*lidx*/ 0, /*mode*/ 0, /*doMlp*/ 0,
      /*tbase*/ basin_coords, /*temp_w*/ temp_w, /*temp_b*/ temp_b,
      /*rs_layers*/ rs_layers, /*xin*/ bseq, /*xout*/ prevb,
      /*Fbo*/ Fb1, /*XTo*/ XT1,
      /*WT*/ nullptr, /*bbias*/ nullptr, /*prevX*/ nullptr,
      /*gateOut*/ nullptr, /*poolPart*/ nullptr,
      /*mlp_pool*/ nullptr, /*basin_coords*/ nullptr,
      /*w1*/ nullptr, /*b1*/ nullptr, /*w2*/ nullptr, /*b2*/ nullptr,
      /*uw*/ nullptr, /*ub*/ nullptr, /*bnew_g*/ nullptr,
      /*bseq*/ nullptr, /*res_scale*/ nullptr, /*outp*/ nullptr);
  // ---- pass 0, layer 1 ----
  layer_k<<<192, 1024, 0, stream>>>(
      /*Fbi*/ Fb1, /*XTi*/ XT1, /*lidx*/ 1, /*mode*/ 0, /*doMlp*/ 0,
      /*tbase*/ basin_coords, /*temp_w*/ temp_w, /*temp_b*/ temp_b,
      /*rs_layers*/ rs_layers, /*xin*/ prevb, /*xout*/ prevb + TD,
      /*Fbo*/ Fb0, /*XTo*/ XT0,
      /*WT*/ nullptr, /*bbias*/ nullptr, /*prevX*/ nullptr,
      /*gateOut*/ nullptr, /*poolPart*/ nullptr,
      /*mlp_pool*/ nullptr, /*basin_coords*/ nullptr,
      /*w1*/ nullptr, /*b1*/ nullptr, /*w2*/ nullptr, /*b2*/ nullptr,
      /*uw*/ nullptr, /*ub*/ nullptr, /*bnew_g*/ nullptr,
      /*bseq*/ nullptr, /*res_scale*/ nullptr, /*outp*/ nullptr);
  // ---- pass 0, layer 2 ----
  layer_k<<<192, 1024, 0, stream>>>(
      /*Fbi*/ Fb0, /*XTi*/ XT0, /*lidx*/ 2, /*mode*/ 0, /*doMlp*/ 0,
      /*tbase*/ basin_coords, /*temp_w*/ temp_w, /*temp_b*/ temp_b,
      /*rs_layers*/ rs_layers, /*xin*/ prevb + TD, /*xout*/ prevb + 2 * TD,
      /*Fbo*/ Fb1, /*XTo*/ XT1,
      /*WT*/ nullptr, /*bbias*/ nullptr, /*prevX*/ nullptr,
      /*gateOut*/ nullptr, /*poolPart*/ nullptr,
      /*mlp_pool*/ nullptr, /*basin_coords*/ nullptr,
      /*w1*/ nullptr, /*b1*/ nullptr, /*w2*/ nullptr, /*b2*/ nullptr,
      /*uw*/ nullptr, /*ub*/ nullptr, /*bnew_g*/ nullptr,
      /*bseq*/ nullptr, /*res_scale*/ nullptr, /*outp*/ nullptr);
  // ---- pass 0, layer 3: residual->prevb3; pool; gate(l0)->xA; feat(gated)->Fb0/XT0 ----
  layer_k<<<192, 1024, 0, stream>>>(
      /*Fbi*/ Fb1, /*XTi*/ XT1, /*lidx*/ 3, /*mode*/ 1, /*doMlp*/ 0,
      /*tbase*/ basin_coords, /*temp_w*/ temp_w, /*temp_b*/ temp_b,
      /*rs_layers*/ rs_layers, /*xin*/ prevb + 2 * TD, /*xout*/ prevb + 3 * TD,
      /*Fbo*/ Fb0, /*XTo*/ XT0,
      /*WT*/ fbwT, /*bbias*/ fb_b, /*prevX*/ prevb,
      /*gateOut*/ xA, /*poolPart*/ poolPart,
      /*mlp_pool*/ nullptr, /*basin_coords*/ nullptr,
      /*w1*/ nullptr, /*b1*/ nullptr, /*w2*/ nullptr, /*b2*/ nullptr,
      /*uw*/ nullptr, /*ub*/ nullptr, /*bnew_g*/ nullptr,
      /*bseq*/ nullptr, /*res_scale*/ nullptr, /*outp*/ nullptr);
  // ---- pass 1, layer 0 (does MLP/basin update in-prologue) ----
  layer_k<<<192, 1024, 0, stream>>>(
      /*Fbi*/ Fb0, /*XTi*/ XT0, /*lidx*/ 0, /*mode*/ 2, /*doMlp*/ 1,
      /*tbase*/ nullptr, /*temp_w*/ temp_w, /*temp_b*/ temp_b,
      /*rs_layers*/ rs_layers, /*xin*/ xA, /*xout*/ xB,
      /*Fbo*/ Fb1, /*XTo*/ XT1,
      /*WT*/ fbwT + 8192, /*bbias*/ fb_b + 64, /*prevX*/ prevb + TD,
      /*gateOut*/ nullptr, /*poolPart*/ nullptr,
      /*mlp_pool*/ poolPart, /*basin_coords*/ basin_coords,
      /*w1*/ comp_w1, /*b1*/ comp_b1, /*w2*/ comp_w2, /*b2*/ comp_b2,
      /*uw*/ upd_w, /*ub*/ upd_b, /*bnew_g*/ bnew_g,
      /*bseq*/ nullptr, /*res_scale*/ nullptr, /*outp*/ nullptr);
  // ---- pass 1, layer 1 ----
  layer_k<<<192, 1024, 0, stream>>>(
      /*Fbi*/ Fb1, /*XTi*/ XT1, /*lidx*/ 1, /*mode*/ 2, /*doMlp*/ 0,
      /*tbase*/ bnew_g, /*temp_w*/ temp_w, /*temp_b*/ temp_b,
      /*rs_layers*/ rs_layers, /*xin*/ xB, /*xout*/ xA,
      /*Fbo*/ Fb0, /*XTo*/ XT0,
      /*WT*/ fbwT + 16384, /*bbias*/ fb_b + 128, /*prevX*/ prevb + 2 * TD,
      /*gateOut*/ nullptr, /*poolPart*/ nullptr,
      /*mlp_pool*/ nullptr, /*basin_coords*/ nullptr,
      /*w1*/ nullptr, /*b1*/ nullptr, /*w2*/ nullptr, /*b2*/ nullptr,
      /*uw*/ nullptr, /*ub*/ nullptr, /*bnew_g*/ nullptr,
      /*bseq*/ nullptr, /*res_scale*/ nullptr, /*outp*/ nullptr);
  // ---- pass 1, layer 2 ----
  layer_k<<<192, 1024, 0, stream>>>(
      /*Fbi*/ Fb0, /*XTi*/ XT0, /*lidx*/ 2, /*mode*/ 2, /*doMlp*/ 0,
      /*tbase*/ bnew_g, /*temp_w*/ temp_w, /*temp_b*/ temp_b,
      /*rs_layers*/ rs_layers, /*xin*/ xA, /*xout*/ xB,
      /*Fbo*/ Fb1, /*XTo*/ XT1,
      /*WT*/ fbwT + 24576, /*bbias*/ fb_b + 192, /*prevX*/ prevb + 3 * TD,
      /*gateOut*/ nullptr, /*poolPart*/ nullptr,
      /*mlp_pool*/ nullptr, /*basin_coords*/ nullptr,
      /*w1*/ nullptr, /*b1*/ nullptr, /*w2*/ nullptr, /*b2*/ nullptr,
      /*uw*/ nullptr, /*ub*/ nullptr, /*bnew_g*/ nullptr,
      /*bseq*/ nullptr, /*res_scale*/ nullptr, /*outp*/ nullptr);
  // ---- pass 1, layer 3: final output ----
  layer_k<<<192, 1024, 0, stream>>>(
      /*Fbi*/ Fb1, /*XTi*/ XT1, /*lidx*/ 3, /*mode*/ 3, /*doMlp*/ 0,
      /*tbase*/ bnew_g, /*temp_w*/ temp_w, /*temp_b*/ temp_b,
      /*rs_layers*/ rs_layers, /*xin*/ xB, /*xout*/ nullptr,
      /*Fbo*/ nullptr, /*XTo*/ nullptr,
      /*WT*/ nullptr, /*bbias*/ nullptr, /*prevX*/ nullptr,
      /*gateOut*/ nullptr, /*poolPart*/ nullptr,
      /*mlp_pool*/ nullptr, /*basin_coords*/ nullptr,
      /*w1*/ nullptr, /*b1*/ nullptr, /*w2*/ nullptr, /*b2*/ nullptr,
      /*uw*/ nullptr, /*ub*/ nullptr, /*bnew_g*/ nullptr,
      /*bseq*/ bseq, /*res_scale*/ res_scale, /*outp*/ out);
}

// Round 14
// 118.746 us; speedup vs baseline: 3.5479x; 1.0746x over previous
//
#include <hip/hip_runtime.h>
#include <math.h>

#define T_ 768
#define TD (T_*64)
#define EPSF 1e-8f

typedef __attribute__((ext_vector_type(8))) short short8;
typedef __attribute__((ext_vector_type(4))) float f32x4;

__device__ __forceinline__ float wave_sum64(float v) {
#pragma unroll
  for (int m = 32; m >= 1; m >>= 1) v += __shfl_xor(v, m, 64);
  return v;
}
__device__ __forceinline__ float sigmoidf_(float x) { return 1.0f / (1.0f + expf(-x)); }

__device__ __forceinline__ unsigned short f2bf(float x) {
  unsigned int u = __float_as_uint(x);
  u += 0x7fffu + ((u >> 16) & 1u);        // RNE
  return (unsigned short)(u >> 16);
}

// acos(x), x in [0,1): sqrt(1-x)*poly3, |err|<=6.7e-5 (A-S 4.4.45)
__device__ __forceinline__ float acos_pos(float x) {
  float s = sqrtf(fmaxf(1.0f - x, 0.0f));
  return s * (1.5707288f + x * (-0.2121144f + x * (0.0742610f + x * (-0.0187293f))));
}

// simplex proj + renorm; feature row f = sqrt(p) (64 bf16).
__device__ __forceinline__ void feat_bf(float v, int row, int lane,
                                        unsigned short* __restrict__ Fb) {
  float sp = fmaxf(v, 0.0f) + log1pf(expf(-fabsf(v)));
  float s = wave_sum64(sp);
  float p1 = fmaxf(sp / (s + EPSF), EPSF);
  float s2 = wave_sum64(p1);
  float p = p1 / (s2 + EPSF);
  Fb[row * 64 + lane] = f2bf(sqrtf(p));
}

// features(bseq) + XT(bseq) + fb_w transpose. grid 192x256.
__global__ void __launch_bounds__(256)
phaseA_kernel(const float* __restrict__ bseq, const float* __restrict__ fb_w,
              unsigned short* __restrict__ Fb, unsigned short* __restrict__ XTb,
              float* __restrict__ fbwT) {
  int b = blockIdx.x, tid = threadIdx.x, w = tid >> 6, l = tid & 63;
  int row = b * 4 + w;
  float v = bseq[row * 64 + l];
  feat_bf(v, row, l, Fb);
  XTb[l * 768 + row] = f2bf(v);
  if (b < 128) {                          // 128*256 = 4*64*128
    int idx = b * 256 + tid;
    int ll = idx >> 13, r = idx & 8191, d = r >> 7, k = r & 127;
    fbwT[ll * 8192 + k * 64 + d] = fb_w[ll * 8192 + d * 128 + k];
  }
}

// One dispatch per layer. 192 blocks x 1024 thr (16 waves, 4 waves/SIMD);
// block owns rows 4b..4b+3. A-row dup: A tile row lr holds F[i0+(lr&3)].
// F and XT are bulk-staged into LDS (coalesced streams); MFMA frags from LDS.
// mode 0: plain+feat; 1: pool + gate(l0) + feat(gated); 2: gate+feat; 3: final
__global__ void __launch_bounds__(1024)
layer_k(const unsigned short* __restrict__ Fbi,
        const unsigned short* __restrict__ XTi,
        int lidx, int mode, int doMlp,
        const float* __restrict__ tbase,     // basin_coords (steps 0-3) / bnew_g (5-7)
        const float* __restrict__ temp_w, const float* __restrict__ temp_b,
        const float* __restrict__ rs_layers,
        const float* __restrict__ xin, float* __restrict__ xout,
        unsigned short* __restrict__ Fbo, unsigned short* __restrict__ XTo,
        const float* __restrict__ WT, const float* __restrict__ bbias,
        const float* __restrict__ prevX,
        float* __restrict__ gateOut, float* __restrict__ poolPart,
        const float* __restrict__ mlp_pool, const float* __restrict__ basin_coords,
        const float* __restrict__ w1, const float* __restrict__ b1,
        const float* __restrict__ w2, const float* __restrict__ b2,
        const float* __restrict__ uw, const float* __restrict__ ub,
        float* __restrict__ bnew_g,
        const float* __restrict__ bseq, const float* __restrict__ res_scale,
        float* __restrict__ outp) {
  __shared__ __align__(16) float4 stageBuf[6208];       // F: 6144 f4 | XT padded: 64x97 f4
  __shared__ __align__(16) unsigned short Pl[4][776];   // P numerators bf16
  __shared__ float sums16[16][4];                       // [wave][query]
  __shared__ float pvs[4][4][64];                       // [K-quarter][query][col]
  __shared__ float xs[4][64], ps[4][64];
  __shared__ float part16[16][64];
  __shared__ float pooled[64], h1s[32], aggs[64], bnewS[64];
  int tid = threadIdx.x, w = tid >> 6, l = tid & 63;
  int lr = l & 15, lk = l >> 4;
  int b = blockIdx.x, i0 = b * 4;
  unsigned short* stage_s = reinterpret_cast<unsigned short*>(stageBuf);

  // ---- temperature (and redundant MLP+basin update on step 4) ----
  float temp;
  if (doMlp) {
    {
      float s = 0.f;
      for (int bb2 = w * 12; bb2 < w * 12 + 12; bb2++) s += mlp_pool[bb2 * 64 + l];
      part16[w][l] = s;
    }
    __syncthreads();
    if (tid < 64) {
      float s = 0.f;
#pragma unroll
      for (int q = 0; q < 16; q++) s += part16[q][tid];
      pooled[tid] = s * (1.0f / 768.0f);
    }
    __syncthreads();
    if (tid < 32) {
      float h = b1[tid];
      for (int k = 0; k < 64; k++) h += w1[tid * 64 + k] * pooled[k];
      h1s[tid] = tanhf(h);
    }
    __syncthreads();
    if (tid < 64) {
      float h = b2[tid];
      for (int k = 0; k < 32; k++) h += w2[tid * 32 + k] * h1s[k];
      aggs[tid] = tanhf(h);
    }
    __syncthreads();
    if (tid < 64) {
      float g = ub[tid];
      for (int k = 0; k < 64; k++) g += uw[tid * 128 + k] * basin_coords[k];
      for (int k = 0; k < 64; k++) g += uw[tid * 128 + 64 + k] * aggs[k];
      g = sigmoidf_(g);
      bnewS[tid] = basin_coords[tid] * (1.0f - g) + aggs[tid] * g;
    }
    __syncthreads();
    if (b == 0 && tid < 64) bnew_g[tid] = bnewS[tid];   // publish for steps 5-7
    float v = bnewS[l] * temp_w[lidx * 64 + l];
    v = wave_sum64(v);
    temp = sigmoidf_(v + temp_b[lidx]) + 0.5f;
  } else {
    float v = tbase[l] * temp_w[lidx * 64 + l];
    v = wave_sum64(v);
    temp = sigmoidf_(v + temp_b[lidx]) + 0.5f;
  }
  float inv_t = 1.0f / fmaxf(temp, 1e-6f);

  // ---- stage F (96KB, linear) into LDS: 6 coalesced float4 per thread ----
  {
    const float4* src = reinterpret_cast<const float4*>(Fbi);
    float4 v0 = src[tid],        v1 = src[tid + 1024], v2 = src[tid + 2048];
    float4 v3 = src[tid + 3072], v4 = src[tid + 4096], v5 = src[tid + 5120];
    stageBuf[tid] = v0;        stageBuf[tid + 1024] = v1; stageBuf[tid + 2048] = v2;
    stageBuf[tid + 3072] = v3; stageBuf[tid + 4096] = v4; stageBuf[tid + 5120] = v5;
  }
  __syncthreads();

  // ---- QK Gram (K=64, frags from LDS): wave w: j-tiles 3w..3w+2 ----
  const short8* arow = reinterpret_cast<const short8*>(stage_s + (i0 + (lr & 3)) * 64);
  short8 afr0 = arow[lk], afr1 = arow[4 + lk];

  float sp[4] = {0.f, 0.f, 0.f, 0.f};
#pragma unroll
  for (int jj = 0; jj < 3; jj++) {
    int jt = w * 3 + jj;
    const short8* brow = reinterpret_cast<const short8*>(stage_s + (jt * 16 + lr) * 64);
    f32x4 acc = {0.f, 0.f, 0.f, 0.f};
    acc = __builtin_amdgcn_mfma_f32_16x16x32_bf16(afr0, brow[lk], acc, 0, 0, 0);
    acc = __builtin_amdgcn_mfma_f32_16x16x32_bf16(afr1, brow[4 + lk], acc, 0, 0, 0);
#pragma unroll
    for (int r = 0; r < 4; r++) {
      float inner = fminf(fmaxf(acc[r], 0.0f), 1.0f - 1e-6f);
      float e = expf(-2.0f * acos_pos(inner) * inv_t);   // max logit ~0: no-max safe
      if (lk == 0) Pl[r][jt * 16 + lr] = f2bf(e);
      sp[r] += e;                                        // lk-copies identical
    }
  }
#pragma unroll
  for (int m = 1; m <= 8; m <<= 1)
#pragma unroll
    for (int r = 0; r < 4; r++) sp[r] += __shfl_xor(sp[r], m, 64);
  if (l == 0)
#pragma unroll
    for (int r = 0; r < 4; r++) sums16[w][r] = sp[r];
  __syncthreads();            // QK done: F reads finished, Pl/sums ready

  // ---- stage XT (96KB -> padded 64x776 shorts = 64x97 f4) into same LDS ----
  {
    const float4* src = reinterpret_cast<const float4*>(XTi);
#pragma unroll
    for (int rnd = 0; rnd < 3; rnd++) {
      int i0f = tid + rnd * 2048;          // two chunks per round
      int i1f = i0f + 1024;
      float4 va = src[i0f], vb = src[i1f];
      stageBuf[i0f + i0f / 96] = va;       // dst row stride 97 f4 (776 shorts)
      stageBuf[i1f + i1f / 96] = vb;
    }
  }
  __syncthreads();

  // ---- PV (frags from LDS): wave (cg=w&3, kq=w>>2): cols cg*16..+15, K-quarter kq ----
  {
    int cg = w & 3, kq = w >> 2;
    f32x4 pA = {0.f, 0.f, 0.f, 0.f}, pB = {0.f, 0.f, 0.f, 0.f};
    const short8* xtrow =
        reinterpret_cast<const short8*>(stage_s + (cg * 16 + lr) * 776 + kq * 192);
#pragma unroll
    for (int ks = 0; ks < 3; ks++) {
      short8 paA = *reinterpret_cast<const short8*>(&Pl[lr & 3][kq * 192 + ks * 32 + lk * 8]);
      short8 paB = *reinterpret_cast<const short8*>(&Pl[lr & 3][kq * 192 + (ks + 3) * 32 + lk * 8]);
      pA = __builtin_amdgcn_mfma_f32_16x16x32_bf16(paA, xtrow[ks * 4 + lk], pA, 0, 0, 0);
      pB = __builtin_amdgcn_mfma_f32_16x16x32_bf16(paB, xtrow[(ks + 3) * 4 + lk], pB, 0, 0, 0);
    }
    if (lk == 0)
#pragma unroll
      for (int r = 0; r < 4; r++) pvs[kq][r][cg * 16 + lr] = pA[r] + pB[r];
  }
  __syncthreads();

  // ---- normalize + residual: wave-groups all handle row rw=w&3 (idempotent) ----
  int rw = w & 3;
  int row = i0 + rw;
  float stot = 0.f;
#pragma unroll
  for (int q = 0; q < 16; q++) stot += sums16[q][rw];
  float attn = ((pvs[0][rw][l] + pvs[1][rw][l]) + (pvs[2][rw][l] + pvs[3][rw][l])) / stot;
  float xi = xin[row * 64 + l];
  float xo = xi + rs_layers[lidx] * (attn - xi);
  xs[rw][l] = xo;                          // duplicate identical writes: benign
  if (mode == 1 || mode == 2) ps[rw][l] = prevX[row * 64 + l];
  __syncthreads();

  // ---- tails (wave-groups mirror; all writes idempotent) ----
  if (mode == 3) {
    outp[row * 64 + l] = xo + 0.01f * res_scale[0] * (xo - bseq[row * 64 + l]);
    return;
  }
  if (mode == 0) {
    xout[row * 64 + l] = xo;
    XTo[l * 768 + row] = f2bf(xo);
    feat_bf(xo, row, l, Fbo);
    return;
  }
  // gate: a = bbias + [x, prev] . W^T   (WT is (128,64) k-major)
  float a = bbias[l];
#pragma unroll 8
  for (int k = 0; k < 64; k++) a += xs[rw][k] * WT[k * 64 + l];
#pragma unroll 8
  for (int k = 0; k < 64; k++) a += ps[rw][k] * WT[(64 + k) * 64 + l];
  float g = sigmoidf_(a);
  float xn = xo * g + ps[rw][l] * (1.0f - g);
  if (mode == 1) {
    xout[row * 64 + l] = xo;              // ungated pass0-l3 out (prev for pass1 l3)
    gateOut[row * 64 + l] = xn;           // pass1 l0 input
  } else {
    xout[row * 64 + l] = xn;
  }
  XTo[l * 768 + row] = f2bf(xn);
  feat_bf(xn, row, l, Fbo);
  if (mode == 1 && w == 0)
    poolPart[b * 64 + l] = xs[0][l] + xs[1][l] + xs[2][l] + xs[3][l];
}

extern "C" void kernel_launch(void* const* d_in, const int* in_sizes, int n_in,
                              void* d_out, int out_size, void* d_ws, size_t ws_size,
                              hipStream_t stream) {
  const float* bseq         = (const float*)d_in[0];
  const float* basin_coords = (const float*)d_in[1];
  const float* temp_w       = (const float*)d_in[2];
  const float* temp_b       = (const float*)d_in[3];
  const float* rs_layers    = (const float*)d_in[4];
  const float* fb_w         = (const float*)d_in[5];
  const float* fb_b         = (const float*)d_in[6];
  const float* comp_w1      = (const float*)d_in[7];
  const float* comp_b1      = (const float*)d_in[8];
  const float* comp_w2      = (const float*)d_in[9];
  const float* comp_b2      = (const float*)d_in[10];
  const float* upd_w        = (const float*)d_in[11];
  const float* upd_b        = (const float*)d_in[12];
  const float* res_scale    = (const float*)d_in[13];
  float* out = (float*)d_out;

  float* ws = (float*)d_ws;
  float* xA       = ws;                    // TD
  float* xB       = xA + TD;               // TD
  float* prevb    = xB + TD;               // 4*TD
  float* fbwT     = prevb + 4 * TD;        // 32768
  float* poolPart = fbwT + 32768;          // 192*64
  float* bnew_g   = poolPart + 12288;      // 64 (pad 80)
  unsigned short* Fb0 = (unsigned short*)(bnew_g + 80);  // 768*64 bf16
  unsigned short* Fb1 = Fb0 + 49152;
  unsigned short* XT0 = Fb1 + 49152;       // 64*768 bf16
  unsigned short* XT1 = XT0 + 49152;

  phaseA_kernel<<<192, 256, 0, stream>>>(bseq, fb_w, Fb0, XT0, fbwT);

  // ---- pass 0, layer 0 ----
  layer_k<<<192, 1024, 0, stream>>>(
      /*Fbi*/ Fb0, /*XTi*/ XT0, /*lidx*/ 0, /*mode*/ 0, /*doMlp*/ 0,
      /*tbase*/ basin_coords, /*temp_w*/ temp_w, /*temp_b*/ temp_b,
      /*rs_layers*/ rs_layers, /*xin*/ bseq, /*xout*/ prevb,
      /*Fbo*/ Fb1, /*XTo*/ XT1,
      /*WT*/ nullptr, /*bbias*/ nullptr, /*prevX*/ nullptr,
      /*gateOut*/ nullptr, /*poolPart*/ nullptr,
      /*mlp_pool*/ nullptr, /*basin_coords*/ nullptr,
      /*w1*/ nullptr, /*b1*/ nullptr, /*w2*/ nullptr, /*b2*/ nullptr,
      /*uw*/ nullptr, /*ub*/ nullptr, /*bnew_g*/ nullptr,
      /*bseq*/ nullptr, /*res_scale*/ nullptr, /*outp*/ nullptr);
  // ---- pass 0, layer 1 ----
  layer_k<<<192, 1024, 0, stream>>>(
      /*Fbi*/ Fb1, /*XTi*/ XT1, /*lidx*/ 1, /*mode*/ 0, /*doMlp*/ 0,
      /*tbase*/ basin_coords, /*temp_w*/ temp_w, /*temp_b*/ temp_b,
      /*rs_layers*/ rs_layers, /*xin*/ prevb, /*xout*/ prevb + TD,
      /*Fbo*/ Fb0, /*XTo*/ XT0,
      /*WT*/ nullptr, /*bbias*/ nullptr, /*prevX*/ nullptr,
      /*gateOut*/ nullptr, /*poolPart*/ nullptr,
      /*mlp_pool*/ nullptr, /*basin_coords*/ nullptr,
      /*w1*/ nullptr, /*b1*/ nullptr, /*w2*/ nullptr, /*b2*/ nullptr,
      /*uw*/ nullptr, /*ub*/ nullptr, /*bnew_g*/ nullptr,
      /*bseq*/ nullptr, /*res_scale*/ nullptr, /*outp*/ nullptr);
  // ---- pass 0, layer 2 ----
  layer_k<<<192, 1024, 0, stream>>>(
      /*Fbi*/ Fb0, /*XTi*/ XT0, /*lidx*/ 2, /*mode*/ 0, /*doMlp*/ 0,
      /*tbase*/ basin_coords, /*temp_w*/ temp_w, /*temp_b*/ temp_b,
      /*rs_layers*/ rs_layers, /*xin*/ prevb + TD, /*xout*/ prevb + 2 * TD,
      /*Fbo*/ Fb1, /*XTo*/ XT1,
      /*WT*/ nullptr, /*bbias*/ nullptr, /*prevX*/ nullptr,
      /*gateOut*/ nullptr, /*poolPart*/ nullptr,
      /*mlp_pool*/ nullptr, /*basin_coords*/ nullptr,
      /*w1*/ nullptr, /*b1*/ nullptr, /*w2*/ nullptr, /*b2*/ nullptr,
      /*uw*/ nullptr, /*ub*/ nullptr, /*bnew_g*/ nullptr,
      /*bseq*/ nullptr, /*res_scale*/ nullptr, /*outp*/ nullptr);
  // ---- pass 0, layer 3: residual->prevb3; pool; gate(l0)->xA; feat(gated)->Fb0/XT0 ----
  layer_k<<<192, 1024, 0, stream>>>(
      /*Fbi*/ Fb1, /*XTi*/ XT1, /*lidx*/ 3, /*mode*/ 1, /*doMlp*/ 0,
      /*tbase*/ basin_coords, /*temp_w*/ temp_w, /*temp_b*/ temp_b,
      /*rs_layers*/ rs_layers, /*xin*/ prevb + 2 * TD, /*xout*/ prevb + 3 * TD,
      /*Fbo*/ Fb0, /*XTo*/ XT0,
      /*WT*/ fbwT, /*bbias*/ fb_b, /*prevX*/ prevb,
      /*gateOut*/ xA, /*poolPart*/ poolPart,
      /*mlp_pool*/ nullptr, /*basin_coords*/ nullptr,
      /*w1*/ nullptr, /*b1*/ nullptr, /*w2*/ nullptr, /*b2*/ nullptr,
      /*uw*/ nullptr, /*ub*/ nullptr, /*bnew_g*/ nullptr,
      /*bseq*/ nullptr, /*res_scale*/ nullptr, /*outp*/ nullptr);
  // ---- pass 1, layer 0 (does MLP/basin update in-prologue) ----
  layer_k<<<192, 1024, 0, stream>>>(
      /*Fbi*/ Fb0, /*XTi*/ XT0, /*lidx*/ 0, /*mode*/ 2, /*doMlp*/ 1,
      /*tbase*/ nullptr, /*temp_w*/ temp_w, /*temp_b*/ temp_b,
      /*rs_layers*/ rs_layers, /*xin*/ xA, /*xout*/ xB,
      /*Fbo*/ Fb1, /*XTo*/ XT1,
      /*WT*/ fbwT + 8192, /*bbias*/ fb_b + 64, /*prevX*/ prevb + TD,
      /*gateOut*/ nullptr, /*poolPart*/ nullptr,
      /*mlp_pool*/ poolPart, /*basin_coords*/ basin_coords,
      /*w1*/ comp_w1, /*b1*/ comp_b1, /*w2*/ comp_w2, /*b2*/ comp_b2,
      /*uw*/ upd_w, /*ub*/ upd_b, /*bnew_g*/ bnew_g,
      /*bseq*/ nullptr, /*res_scale*/ nullptr, /*outp*/ nullptr);
  // ---- pass 1, layer 1 ----
  layer_k<<<192, 1024, 0, stream>>>(
      /*Fbi*/ Fb1, /*XTi*/ XT1, /*lidx*/ 1, /*mode*/ 2, /*doMlp*/ 0,
      /*tbase*/ bnew_g, /*temp_w*/ temp_w, /*temp_b*/ temp_b,
      /*rs_layers*/ rs_layers, /*xin*/ xB, /*xout*/ xA,
      /*Fbo*/ Fb0, /*XTo*/ XT0,
      /*WT*/ fbwT + 16384, /*bbias*/ fb_b + 128, /*prevX*/ prevb + 2 * TD,
      /*gateOut*/ nullptr, /*poolPart*/ nullptr,
      /*mlp_pool*/ nullptr, /*basin_coords*/ nullptr,
      /*w1*/ nullptr, /*b1*/ nullptr, /*w2*/ nullptr, /*b2*/ nullptr,
      /*uw*/ nullptr, /*ub*/ nullptr, /*bnew_g*/ nullptr,
      /*bseq*/ nullptr, /*res_scale*/ nullptr, /*outp*/ nullptr);
  // ---- pass 1, layer 2 ----
  layer_k<<<192, 1024, 0, stream>>>(
      /*Fbi*/ Fb0, /*XTi*/ XT0, /*lidx*/ 2, /*mode*/ 2, /*doMlp*/ 0,
      /*tbase*/ bnew_g, /*temp_w*/ temp_w, /*temp_b*/ temp_b,
      /*rs_layers*/ rs_layers, /*xin*/ xA, /*xout*/ xB,
      /*Fbo*/ Fb1, /*XTo*/ XT1,
      /*WT*/ fbwT + 24576, /*bbias*/ fb_b + 192, /*prevX*/ prevb + 3 * TD,
      /*gateOut*/ nullptr, /*poolPart*/ nullptr,
      /*mlp_pool*/ nullptr, /*basin_coords*/ nullptr,
      /*w1*/ nullptr, /*b1*/ nullptr, /*w2*/ nullptr, /*b2*/ nullptr,
      /*uw*/ nullptr, /*ub*/ nullptr, /*bnew_g*/ nullptr,
      /*bseq*/ nullptr, /*res_scale*/ nullptr, /*outp*/ nullptr);
  // ---- pass 1, layer 3: final output ----
  layer_k<<<192, 1024, 0, stream>>>(
      /*Fbi*/ Fb1, /*XTi*/ XT1, /*lidx*/ 3, /*mode*/ 3, /*doMlp*/ 0,
      /*tbase*/ bnew_g, /*temp_w*/ temp_w, /*temp_b*/ temp_b,
      /*rs_layers*/ rs_layers, /*xin*/ xB, /*xout*/ nullptr,
      /*Fbo*/ nullptr, /*XTo*/ nullptr,
      /*WT*/ nullptr, /*bbias*/ nullptr, /*prevX*/ nullptr,
      /*gateOut*/ nullptr, /*poolPart*/ nullptr,
      /*mlp_pool*/ nullptr, /*basin_coords*/ nullptr,
      /*w1*/ nullptr, /*b1*/ nullptr, /*w2*/ nullptr, /*b2*/ nullptr,
      /*uw*/ nullptr, /*ub*/ nullptr, /*bnew_g*/ nullptr,
      /*bseq*/ bseq, /*res_scale*/ res_scale, /*outp*/ out);
}